// Round 16
// baseline (209.408 us; speedup 1.0000x reference)
//
#include <hip/hip_runtime.h>

#define T 32
#define C 2048
#define NTOT 600
#define NCLASS 20
#define NSUP 5
#define PER 30
#define NQPC 25
#define NQ 500
#define NQROWS (NQ * T)      // 16000
#define NPROWS (NCLASS * T)  // 640
#define GAMMA 0.1f
#define INVG 10.0f
#define BIG 1e10f
#define NMM (NQ * NCLASS + NQ + NCLASS)  // 10520
#define GEMM_BLKS 625
#define SYRK_BLKS_PAD 136  // multiple of 8 so gemm swizzle sees o%8 unchanged
#define STAGE_BLKS_A 2000  // (16000/16 rows) x 2 halves
#define STAGE_BLKS_B 80    // (640/16) x 2
// Tiled chunk-major staged layout: idx(row,chunk) = (row/16)*4096 + chunk*16 + row%16
#define TILE_STRIDE 4096   // half8 units per 16-row tile (256 chunks x 16 rows)

typedef __fp16 half8 __attribute__((ext_vector_type(8)));
typedef float f32x4 __attribute__((ext_vector_type(4)));

// ---------------- parallel stable counting sort (1 block) ----------------
__global__ __launch_bounds__(640) void sort_kernel(const int* __restrict__ target,
                                                   int* __restrict__ order,
                                                   int* __restrict__ qsrc) {
    __shared__ int tgt[NTOT];
    __shared__ int offs[NCLASS];
    __shared__ int ordl[NTOT];
    int tid = threadIdx.x;
    if (tid < NTOT) tgt[tid] = target[tid];
    __syncthreads();
    if (tid < NCLASS) {
        int o = 0;
        for (int i = 0; i < NTOT; i++) o += (tgt[i] < tid) ? 1 : 0;
        offs[tid] = o;
    }
    __syncthreads();
    if (tid < NTOT) {
        int c = tgt[tid];
        int rank = 0;
        for (int k = 0; k < NTOT; k++) rank += (k < tid && tgt[k] == c) ? 1 : 0;
        ordl[offs[c] + rank] = tid;
    }
    __syncthreads();
    if (tid < NTOT) order[tid] = ordl[tid];
    if (tid < NQ) qsrc[tid] = ordl[(tid / NQPC) * PER + NSUP + (tid % NQPC)];
}

// ---------------- streaming staging: gather/mean + f16 round, TILED layout --------
// dst idx = tile*4096 + chunk*16 + row16. Per store instr: 4 x 256B runs inside 4KB.
__global__ __launch_bounds__(512) void stage_kernel(const float* __restrict__ inp,
                                                    const int* __restrict__ qsrc,
                                                    const int* __restrict__ order,
                                                    half8* __restrict__ Ah,
                                                    half8* __restrict__ Bh) {
    int bid = blockIdx.x;
    int tid = threadIdx.x;
    int row = tid & 15, seg = tid >> 4;  // seg 0..31
    bool isA = bid < STAGE_BLKS_A;
    int b = isA ? bid : bid - STAGE_BLKS_A;
    int rowblk = b >> 1, half = b & 1;   // rowblk == 16-row tile index
    int rowg = rowblk * 16 + row;
    int col0 = half * 1024 + seg * 32;
    int chunk0 = half * 128 + seg * 4;
    float vals[32];
    if (isA) {
        const float* src = inp + (size_t)qsrc[rowg >> 5] * (T * C) + (size_t)(rowg & 31) * C + col0;
#pragma unroll
        for (int i = 0; i < 8; i++) {
            float4 v = *(const float4*)(src + i * 4);
            vals[i * 4 + 0] = v.x; vals[i * 4 + 1] = v.y;
            vals[i * 4 + 2] = v.z; vals[i * 4 + 3] = v.w;
        }
        half8 hv[4];
#pragma unroll
        for (int e = 0; e < 32; e++) hv[e >> 3][e & 7] = (__fp16)vals[e];
#pragma unroll
        for (int c = 0; c < 4; c++)
            Ah[(size_t)rowblk * TILE_STRIDE + (size_t)(chunk0 + c) * 16 + row] = hv[c];
    } else {
        int cls = rowg >> 5, trow = rowg & 31;
        const float* base = inp + (size_t)trow * C + col0;
        const float* s0 = base + (size_t)order[cls * PER + 0] * (T * C);
        const float* s1 = base + (size_t)order[cls * PER + 1] * (T * C);
        const float* s2 = base + (size_t)order[cls * PER + 2] * (T * C);
        const float* s3 = base + (size_t)order[cls * PER + 3] * (T * C);
        const float* s4 = base + (size_t)order[cls * PER + 4] * (T * C);
#pragma unroll
        for (int i = 0; i < 8; i++) {
            float4 a = *(const float4*)(s0 + i * 4);
            float4 b4 = *(const float4*)(s1 + i * 4);
            float4 c = *(const float4*)(s2 + i * 4);
            float4 d = *(const float4*)(s3 + i * 4);
            float4 e = *(const float4*)(s4 + i * 4);
            vals[i * 4 + 0] = (a.x + b4.x + c.x + d.x + e.x) * 0.2f;
            vals[i * 4 + 1] = (a.y + b4.y + c.y + d.y + e.y) * 0.2f;
            vals[i * 4 + 2] = (a.z + b4.z + c.z + d.z + e.z) * 0.2f;
            vals[i * 4 + 3] = (a.w + b4.w + c.w + d.w + e.w) * 0.2f;
        }
        half8 hv[4];
#pragma unroll
        for (int e = 0; e < 32; e++) hv[e >> 3][e & 7] = (__fp16)vals[e];
#pragma unroll
        for (int c = 0; c < 4; c++)
            Bh[(size_t)rowblk * TILE_STRIDE + (size_t)(chunk0 + c) * 16 + row] = hv[c];
    }
}

// ---------------- merged: SYRK (blocks 0..135) + 1-term register-direct f16 GEMM --
// Tiled layout -> every fragment load instruction is 1KB CONTIGUOUS (64 lanes x 16B,
// 4 chunk-groups x 16 rows adjacent). NO LDS, NO barriers (R10 schedule).
__global__ __launch_bounds__(256) void gemm_syrk_kernel(const half8* __restrict__ Ah,
                                                        const half8* __restrict__ Bh,
                                                        float* __restrict__ xy,
                                                        float* __restrict__ gxx,
                                                        float* __restrict__ gyy) {
    int tid = threadIdx.x, lane = tid & 63, wid = tid >> 6;
    int o = blockIdx.x;
    int g = lane >> 4, r = lane & 15;
    if (o < SYRK_BLKS_PAD) {
        // ---- SYRK path: one wave per 32x32 Gram matrix (short blocks first) ----
        int ww = o * 4 + wid;
        if (ww >= NQ + NCLASS) return;
        const half8* hi;
        int row0;
        float* outp;
        if (ww < NQ) {
            hi = Ah; row0 = ww * 32;
            outp = gxx + (size_t)ww * (T * T);
        } else {
            hi = Bh; row0 = (ww - NQ) * 32;
            outp = gyy + (size_t)(ww - NQ) * (T * T);
        }
        const half8* p = hi + (size_t)(row0 >> 4) * TILE_STRIDE + g * 16 + r;
        f32x4 acc[2][2];
        f32x4 zero = {0.f, 0.f, 0.f, 0.f};
        acc[0][0] = zero; acc[0][1] = zero; acc[1][0] = zero; acc[1][1] = zero;
        for (int t = 0; t < C / 32; t++) {
            half8 h0 = p[0], h1 = p[TILE_STRIDE];
            p += 64;  // next 4 chunks
            acc[0][0] = __builtin_amdgcn_mfma_f32_16x16x32_f16(h0, h0, acc[0][0], 0, 0, 0);
            acc[0][1] = __builtin_amdgcn_mfma_f32_16x16x32_f16(h0, h1, acc[0][1], 0, 0, 0);
            acc[1][0] = __builtin_amdgcn_mfma_f32_16x16x32_f16(h1, h0, acc[1][0], 0, 0, 0);
            acc[1][1] = __builtin_amdgcn_mfma_f32_16x16x32_f16(h1, h1, acc[1][1], 0, 0, 0);
        }
#pragma unroll
        for (int mi = 0; mi < 2; mi++)
#pragma unroll
            for (int ni = 0; ni < 2; ni++)
#pragma unroll
                for (int j = 0; j < 4; j++)
                    outp[(mi * 16 + g * 4 + j) * T + ni * 16 + r] = acc[mi][ni][j];
        return;
    }
    // ---- GEMM path: xy = Ah*Bh^T, 1 MFMA term, register-direct ----
    int oo = o - SYRK_BLKS_PAD;  // 0..624; SYRK_BLKS_PAD%8==0 keeps oo%8==o%8
    int xcd = oo & 7, slot = oo >> 3;
    int v = (xcd < 1 ? xcd * 79 : 79 + (xcd - 1) * 78) + slot;  // bijective over 625=8*78+1
    int bm = v / 5, bn = v % 5;
    int wr = wid >> 1, wc = wid & 1;
    int m0 = bm * 128 + wr * 64, n0 = bn * 128 + wc * 64;  // this wave's 64x64 tile
    const half8* pA = Ah + (size_t)(m0 >> 4) * TILE_STRIDE + g * 16 + r;
    const half8* pB = Bh + (size_t)(n0 >> 4) * TILE_STRIDE + g * 16 + r;
    f32x4 acc[4][4];
    f32x4 zero = {0.f, 0.f, 0.f, 0.f};
#pragma unroll
    for (int mi = 0; mi < 4; mi++)
#pragma unroll
        for (int ni = 0; ni < 4; ni++) acc[mi][ni] = zero;
#pragma unroll 2
    for (int t = 0; t < C / 32; t++) {
        half8 ah[4], bh[4];
#pragma unroll
        for (int i = 0; i < 4; i++) {
            ah[i] = pA[(size_t)i * TILE_STRIDE];  // fragment row-tiles 16 apart
            bh[i] = pB[(size_t)i * TILE_STRIDE];
        }
        pA += 64;  // next 4 chunks of every row
        pB += 64;
#pragma unroll
        for (int mi = 0; mi < 4; mi++)
#pragma unroll
            for (int ni = 0; ni < 4; ni++)
                acc[mi][ni] = __builtin_amdgcn_mfma_f32_16x16x32_f16(ah[mi], bh[ni], acc[mi][ni], 0, 0, 0);
    }
    int orow = m0 + g * 4;
    int ocol = n0 + r;
#pragma unroll
    for (int mi = 0; mi < 4; mi++)
#pragma unroll
        for (int ni = 0; ni < 4; ni++)
#pragma unroll
            for (int j = 0; j < 4; j++)
                xy[(size_t)(orow + mi * 16 + j) * NPROWS + ocol + ni * 16] = acc[mi][ni][j];
}

// ---------------- extract row norms from Gram diagonals ----------------
__global__ void diag_kernel(const float* __restrict__ gxx, const float* __restrict__ gyy,
                            float* __restrict__ x2, float* __restrict__ y2) {
    int i = blockIdx.x * 256 + threadIdx.x;
    if (i < NQROWS) {
        x2[i] = gxx[(size_t)(i >> 5) * (T * T) + (i & 31) * (T + 1)];
    } else if (i < NQROWS + NPROWS) {
        int j = i - NQROWS;
        y2[j] = gyy[(size_t)(j >> 5) * (T * T) + (j & 31) * (T + 1)];
    }
}

// ---------------- wavefront soft-DTW: 32 lanes = 32 columns, 2 matrices/wave ------
__global__ __launch_bounds__(256) void softdtw_wave_kernel(
        const float* __restrict__ xy, const float* __restrict__ gxx,
        const float* __restrict__ gyy, const float* __restrict__ x2,
        const float* __restrict__ y2, float* __restrict__ dxy,
        float* __restrict__ dxx, float* __restrict__ dyy) {
    int tid = threadIdx.x;
    int j = tid & 31;                       // column within the matrix
    int mm = blockIdx.x * 8 + (tid >> 5);   // 8 matrices per 256-thread block
    bool valid = mm < NMM;
    int mmc = valid ? mm : 0;
    const float* rterm;
    const float* cterm;
    const float* cptr;
    int cstride;
    float* outp;
    if (mmc < NQ * NCLASS) {
        int q = mmc / NCLASS, m = mmc % NCLASS;
        rterm = x2 + q * T;
        cterm = y2 + m * T;
        cptr = xy + (size_t)(q * T) * NPROWS + m * T;
        cstride = NPROWS;
        outp = dxy + mmc;
    } else if (mmc < NQ * NCLASS + NQ) {
        int i = mmc - NQ * NCLASS;
        rterm = x2 + i * T;
        cterm = rterm;
        cptr = gxx + (size_t)i * (T * T);
        cstride = T;
        outp = dxx + i;
    } else {
        int i = mmc - NQ * NCLASS - NQ;
        rterm = y2 + i * T;
        cterm = rterm;
        cptr = gyy + (size_t)i * (T * T);
        cstride = T;
        outp = dyy + i;
    }
    float cjv = cterm[j];      // column term (lane-resident)
    float xreg = rterm[j];     // lane l holds rterm[l]; shuffled per step
    float my_prev = BIG, my_prev2 = BIG;
    int ip = 0 - j; ip = ip < 0 ? 0 : (ip > 31 ? 31 : ip);
    float nxt_xy = cptr[(size_t)ip * cstride + j];
    for (int k = 0; k < 63; k++) {
        float cur_xy = nxt_xy;
        int in = k + 1 - j; in = in < 0 ? 0 : (in > 31 ? 31 : in);
        nxt_xy = cptr[(size_t)in * cstride + j];   // prefetch next anti-diagonal
        float lp = __shfl_up(my_prev, 1, 32);
        float dg = __shfl_up(my_prev2, 1, 32);
        if (j == 0) { lp = BIG; dg = (k == 0) ? 0.f : BIG; }
        float up = my_prev;
        int i = k - j;
        float ai = __shfl(xreg, i & 31, 32);
        float d = ai + cjv - 2.0f * cur_xy;
        float mn = fminf(dg, fminf(up, lp));
        float ssum = __expf((mn - dg) * INVG) + __expf((mn - up) * INVG) +
                     __expf((mn - lp) * INVG);
        float r = d + mn - GAMMA * __logf(ssum);
        bool active = (i >= 0) && (i < 32);
        my_prev2 = my_prev;
        my_prev = active ? r : my_prev;
    }
    if (j == 31 && valid) *outp = my_prev;  // R[31][31]
}

// ---------------- finalize: dist, log-softmax, loss, acc ----------------
__global__ __launch_bounds__(512) void finalize_kernel(const float* __restrict__ dxy,
                                                       const float* __restrict__ dxx,
                                                       const float* __restrict__ dyy,
                                                       float* __restrict__ out) {
    __shared__ float sl[512];
    __shared__ float sa[512];
    int q = threadIdx.x;
    float bl = 0.f, fl = 0.f;
    if (q < NQ) {
        float dxxq = dxx[q];
        int cq = q / NQPC;
        float dd[NCLASS];
#pragma unroll
        for (int m = 0; m < NCLASS; m++)
            dd[m] = dxy[q * NCLASS + m] - 0.5f * (dxxq + dyy[m]);
        float best = dd[0];
        int bi = 0;
#pragma unroll
        for (int m = 1; m < NCLASS; m++) {
            if (dd[m] < best) { best = dd[m]; bi = m; }
        }
        float s = 0.f;
        float dcq = dd[0];
#pragma unroll
        for (int m = 0; m < NCLASS; m++) {
            s += __expf(best - dd[m]);
            if (m == cq) dcq = dd[m];
        }
        float lse = __logf(s) - best;
        bl = dcq + lse;
        out[2 + q] = bl;
        fl = (bi == cq) ? 1.f : 0.f;
    }
    sl[threadIdx.x] = bl;
    sa[threadIdx.x] = fl;
    __syncthreads();
    for (int off = 256; off; off >>= 1) {
        if (threadIdx.x < off) {
            sl[threadIdx.x] += sl[threadIdx.x + off];
            sa[threadIdx.x] += sa[threadIdx.x + off];
        }
        __syncthreads();
    }
    if (threadIdx.x == 0) {
        out[0] = sl[0] / (float)NQ;
        out[1] = sa[0] / (float)NQ;
    }
}

extern "C" void kernel_launch(void* const* d_in, const int* in_sizes, int n_in,
                              void* d_out, int out_size, void* d_ws, size_t ws_size,
                              hipStream_t stream) {
    const float* inp = (const float*)d_in[0];
    const int* target = (const int*)d_in[1];
    float* out = (float*)d_out;
    char* ws = (char*)d_ws;

    size_t off = 0;
    auto carve = [&](size_t bytes) {
        void* p = ws + off;
        off = (off + bytes + 255) & ~(size_t)255;
        return p;
    };
    int* order = (int*)carve(NTOT * sizeof(int));
    int* qsrc = (int*)carve(NQ * sizeof(int));
    float* x2 = (float*)carve((size_t)NQROWS * sizeof(float));
    float* y2 = (float*)carve((size_t)NPROWS * sizeof(float));
    float* xy = (float*)carve((size_t)NQROWS * NPROWS * sizeof(float));  // 41 MB
    float* gxx = (float*)carve((size_t)NQ * T * T * sizeof(float));
    float* gyy = (float*)carve((size_t)NCLASS * T * T * sizeof(float));
    float* dxy = (float*)carve((size_t)NQ * NCLASS * sizeof(float));
    float* dxx = (float*)carve((size_t)NQ * sizeof(float));
    float* dyy = (float*)carve((size_t)NCLASS * sizeof(float));
    half8* Ah = (half8*)carve((size_t)(C / 8) * NQROWS * 16);  // 65.5 MB tiled
    half8* Bh = (half8*)carve((size_t)(C / 8) * NPROWS * 16);  // 2.6 MB (L2-resident)
    (void)ws_size;

    sort_kernel<<<1, 640, 0, stream>>>(target, order, qsrc);
    stage_kernel<<<STAGE_BLKS_A + STAGE_BLKS_B, 512, 0, stream>>>(inp, qsrc, order, Ah, Bh);
    gemm_syrk_kernel<<<SYRK_BLKS_PAD + GEMM_BLKS, 256, 0, stream>>>(Ah, Bh, xy, gxx, gyy);
    diag_kernel<<<(NQROWS + NPROWS + 255) / 256, 256, 0, stream>>>(gxx, gyy, x2, y2);
    softdtw_wave_kernel<<<(NMM + 7) / 8, 256, 0, stream>>>(xy, gxx, gyy, x2, y2, dxy, dxx, dyy);
    finalize_kernel<<<1, 512, 0, stream>>>(dxy, dxx, dyy, out);
}

// Round 17
// 180.409 us; speedup vs baseline: 1.1607x; 1.1607x over previous
//
#include <hip/hip_runtime.h>

#define T 32
#define C 2048
#define NTOT 600
#define NCLASS 20
#define NSUP 5
#define PER 30
#define NQPC 25
#define NQ 500
#define NQROWS (NQ * T)      // 16000
#define NPROWS (NCLASS * T)  // 640
#define GAMMA 0.1f
#define INVG 10.0f
#define BIG 1e10f
#define NMM (NQ * NCLASS + NQ + NCLASS)  // 10520
#define GEMM_BLKS 625
#define SYRK_BLKS_PAD 136  // multiple of 8 so gemm swizzle sees o%8 unchanged
#define STAGE_BLKS_A 2000  // (16000/16 rows) x 2 col-halves
#define STAGE_BLKS_B 80    // (640/16) x 2
#define LDS_PITCH 33       // half8 per LDS row (32 chunks + 1 pad) = 528B

typedef __fp16 half8 __attribute__((ext_vector_type(8)));
typedef __fp16 half4 __attribute__((ext_vector_type(4)));
typedef float f32x4 __attribute__((ext_vector_type(4)));

// ---------------- parallel stable counting sort (1 block) ----------------
__global__ __launch_bounds__(640) void sort_kernel(const int* __restrict__ target,
                                                   int* __restrict__ order,
                                                   int* __restrict__ qsrc) {
    __shared__ int tgt[NTOT];
    __shared__ int offs[NCLASS];
    __shared__ int ordl[NTOT];
    int tid = threadIdx.x;
    if (tid < NTOT) tgt[tid] = target[tid];
    __syncthreads();
    if (tid < NCLASS) {
        int o = 0;
        for (int i = 0; i < NTOT; i++) o += (tgt[i] < tid) ? 1 : 0;
        offs[tid] = o;
    }
    __syncthreads();
    if (tid < NTOT) {
        int c = tgt[tid];
        int rank = 0;
        for (int k = 0; k < NTOT; k++) rank += (k < tid && tgt[k] == c) ? 1 : 0;
        ordl[offs[c] + rank] = tid;
    }
    __syncthreads();
    if (tid < NTOT) order[tid] = ordl[tid];
    if (tid < NQ) qsrc[tid] = ordl[(tid / NQPC) * PER + NSUP + (tid % NQPC)];
}

// ---------------- staging: coalesced reads + wave-local LDS transpose -------------
// Block 256 thr = 16 rows x 1024 cols. Wave = 256-col window. Read: per row, one
// instr where 64 lanes cover 1KB CONTIGUOUS of that row (no redundant line touches).
// LDS transpose (33-half8 pitch, conflict-rotating), then chunk-major writes
// (4 x 256B runs/instr, R15 pattern). Output layout: dst[chunk*nrows + row].
__global__ __launch_bounds__(256) void stage_kernel(const float* __restrict__ inp,
                                                    const int* __restrict__ qsrc,
                                                    const int* __restrict__ order,
                                                    half8* __restrict__ Ah,
                                                    half8* __restrict__ Bh) {
    __shared__ half8 lds[4][16][LDS_PITCH];  // 33.8 KB
    int tid = threadIdx.x;
    int lane = tid & 63, w = tid >> 6;
    int bid = blockIdx.x;
    bool isA = bid < STAGE_BLKS_A;
    int b = isA ? bid : bid - STAGE_BLKS_A;
    int rowblk = b >> 1, half = b & 1;
    int row0 = rowblk * 16;
    int colbase = half * 1024 + w * 256;  // this wave's float-col window
    int nrows = isA ? NQROWS : NPROWS;
    half8* dst = isA ? Ah : Bh;
    if (isA) {
#pragma unroll
        for (int rr = 0; rr < 16; rr++) {
            int rg = row0 + rr;
            const float* src = inp + (size_t)qsrc[rg >> 5] * (T * C) +
                               (size_t)(rg & 31) * C + colbase + lane * 4;
            float4 v = *(const float4*)src;
            half4 hv = {(__fp16)v.x, (__fp16)v.y, (__fp16)v.z, (__fp16)v.w};
            ((half4*)&lds[w][rr][0])[lane] = hv;  // contiguous 512B per wave
        }
    } else {
#pragma unroll
        for (int rr = 0; rr < 16; rr++) {
            int rg = row0 + rr;
            int cls = rg >> 5, trow = rg & 31;
            const float* base = inp + (size_t)trow * C + colbase + lane * 4;
            float4 a = *(const float4*)(base + (size_t)order[cls * PER + 0] * (T * C));
            float4 b4 = *(const float4*)(base + (size_t)order[cls * PER + 1] * (T * C));
            float4 c = *(const float4*)(base + (size_t)order[cls * PER + 2] * (T * C));
            float4 d = *(const float4*)(base + (size_t)order[cls * PER + 3] * (T * C));
            float4 e = *(const float4*)(base + (size_t)order[cls * PER + 4] * (T * C));
            float4 m;
            m.x = (a.x + b4.x + c.x + d.x + e.x) * 0.2f;
            m.y = (a.y + b4.y + c.y + d.y + e.y) * 0.2f;
            m.z = (a.z + b4.z + c.z + d.z + e.z) * 0.2f;
            m.w = (a.w + b4.w + c.w + d.w + e.w) * 0.2f;
            half4 hv = {(__fp16)m.x, (__fp16)m.y, (__fp16)m.z, (__fp16)m.w};
            ((half4*)&lds[w][rr][0])[lane] = hv;
        }
    }
    __syncthreads();
    int chunkbase = half * 128 + w * 32;
#pragma unroll
    for (int c = 0; c < 8; c++) {
        int idx = c * 64 + lane;         // 0..511
        int ch = idx >> 4, row = idx & 15;
        dst[(size_t)(chunkbase + ch) * nrows + row0 + row] = lds[w][row][ch];
    }
}

// ---------------- merged: SYRK (blocks 0..135) + 1-term register-direct f16 GEMM --
// R15 exactly: chunk-major operands, NO LDS, NO barriers, compiler-scheduled.
__global__ __launch_bounds__(256) void gemm_syrk_kernel(const half8* __restrict__ Ah,
                                                        const half8* __restrict__ Bh,
                                                        float* __restrict__ xy,
                                                        float* __restrict__ gxx,
                                                        float* __restrict__ gyy) {
    int tid = threadIdx.x, lane = tid & 63, wid = tid >> 6;
    int o = blockIdx.x;
    int g = lane >> 4, r = lane & 15;
    if (o < SYRK_BLKS_PAD) {
        // ---- SYRK path: one wave per 32x32 Gram matrix (short blocks first) ----
        int ww = o * 4 + wid;
        if (ww >= NQ + NCLASS) return;
        const half8* hi;
        int nrows, row0;
        float* outp;
        if (ww < NQ) {
            hi = Ah; nrows = NQROWS; row0 = ww * 32;
            outp = gxx + (size_t)ww * (T * T);
        } else {
            hi = Bh; nrows = NPROWS; row0 = (ww - NQ) * 32;
            outp = gyy + (size_t)(ww - NQ) * (T * T);
        }
        f32x4 acc[2][2];
        f32x4 zero = {0.f, 0.f, 0.f, 0.f};
        acc[0][0] = zero; acc[0][1] = zero; acc[1][0] = zero; acc[1][1] = zero;
        for (int t = 0; t < C / 32; t++) {
            size_t base = (size_t)(t * 4 + g) * nrows + row0 + r;
            half8 h0 = hi[base], h1 = hi[base + 16];
            acc[0][0] = __builtin_amdgcn_mfma_f32_16x16x32_f16(h0, h0, acc[0][0], 0, 0, 0);
            acc[0][1] = __builtin_amdgcn_mfma_f32_16x16x32_f16(h0, h1, acc[0][1], 0, 0, 0);
            acc[1][0] = __builtin_amdgcn_mfma_f32_16x16x32_f16(h1, h0, acc[1][0], 0, 0, 0);
            acc[1][1] = __builtin_amdgcn_mfma_f32_16x16x32_f16(h1, h1, acc[1][1], 0, 0, 0);
        }
#pragma unroll
        for (int mi = 0; mi < 2; mi++)
#pragma unroll
            for (int ni = 0; ni < 2; ni++)
#pragma unroll
                for (int j = 0; j < 4; j++)
                    outp[(mi * 16 + g * 4 + j) * T + ni * 16 + r] = acc[mi][ni][j];
        return;
    }
    // ---- GEMM path: xy = Ah*Bh^T, 1 MFMA term, register-direct ----
    int oo = o - SYRK_BLKS_PAD;  // 0..624; SYRK_BLKS_PAD%8==0 keeps oo%8==o%8
    int xcd = oo & 7, slot = oo >> 3;
    int v = (xcd < 1 ? xcd * 79 : 79 + (xcd - 1) * 78) + slot;  // bijective over 625=8*78+1
    int bm = v / 5, bn = v % 5;
    int wr = wid >> 1, wc = wid & 1;
    int m0 = bm * 128 + wr * 64, n0 = bn * 128 + wc * 64;  // this wave's 64x64 tile
    const half8* pA = Ah + (size_t)g * NQROWS + m0 + r;
    const half8* pB = Bh + (size_t)g * NPROWS + n0 + r;
    f32x4 acc[4][4];
    f32x4 zero = {0.f, 0.f, 0.f, 0.f};
#pragma unroll
    for (int mi = 0; mi < 4; mi++)
#pragma unroll
        for (int ni = 0; ni < 4; ni++) acc[mi][ni] = zero;
#pragma unroll 2
    for (int t = 0; t < C / 32; t++) {
        half8 ah[4], bh[4];
#pragma unroll
        for (int i = 0; i < 4; i++) {
            ah[i] = pA[i * 16];    // imm offsets 0,256,512,768 B
            bh[i] = pB[i * 16];
        }
        pA += 4 * NQROWS;
        pB += 4 * NPROWS;
#pragma unroll
        for (int mi = 0; mi < 4; mi++)
#pragma unroll
            for (int ni = 0; ni < 4; ni++)
                acc[mi][ni] = __builtin_amdgcn_mfma_f32_16x16x32_f16(ah[mi], bh[ni], acc[mi][ni], 0, 0, 0);
    }
    int orow = m0 + g * 4;
    int ocol = n0 + r;
#pragma unroll
    for (int mi = 0; mi < 4; mi++)
#pragma unroll
        for (int ni = 0; ni < 4; ni++)
#pragma unroll
            for (int j = 0; j < 4; j++)
                xy[(size_t)(orow + mi * 16 + j) * NPROWS + ocol + ni * 16] = acc[mi][ni][j];
}

// ---------------- extract row norms from Gram diagonals ----------------
__global__ void diag_kernel(const float* __restrict__ gxx, const float* __restrict__ gyy,
                            float* __restrict__ x2, float* __restrict__ y2) {
    int i = blockIdx.x * 256 + threadIdx.x;
    if (i < NQROWS) {
        x2[i] = gxx[(size_t)(i >> 5) * (T * T) + (i & 31) * (T + 1)];
    } else if (i < NQROWS + NPROWS) {
        int j = i - NQROWS;
        y2[j] = gyy[(size_t)(j >> 5) * (T * T) + (j & 31) * (T + 1)];
    }
}

// ---------------- wavefront soft-DTW: 32 lanes = 32 columns, 2 matrices/wave ------
__global__ __launch_bounds__(256) void softdtw_wave_kernel(
        const float* __restrict__ xy, const float* __restrict__ gxx,
        const float* __restrict__ gyy, const float* __restrict__ x2,
        const float* __restrict__ y2, float* __restrict__ dxy,
        float* __restrict__ dxx, float* __restrict__ dyy) {
    int tid = threadIdx.x;
    int j = tid & 31;                       // column within the matrix
    int mm = blockIdx.x * 8 + (tid >> 5);   // 8 matrices per 256-thread block
    bool valid = mm < NMM;
    int mmc = valid ? mm : 0;
    const float* rterm;
    const float* cterm;
    const float* cptr;
    int cstride;
    float* outp;
    if (mmc < NQ * NCLASS) {
        int q = mmc / NCLASS, m = mmc % NCLASS;
        rterm = x2 + q * T;
        cterm = y2 + m * T;
        cptr = xy + (size_t)(q * T) * NPROWS + m * T;
        cstride = NPROWS;
        outp = dxy + mmc;
    } else if (mmc < NQ * NCLASS + NQ) {
        int i = mmc - NQ * NCLASS;
        rterm = x2 + i * T;
        cterm = rterm;
        cptr = gxx + (size_t)i * (T * T);
        cstride = T;
        outp = dxx + i;
    } else {
        int i = mmc - NQ * NCLASS - NQ;
        rterm = y2 + i * T;
        cterm = rterm;
        cptr = gyy + (size_t)i * (T * T);
        cstride = T;
        outp = dyy + i;
    }
    float cjv = cterm[j];      // column term (lane-resident)
    float xreg = rterm[j];     // lane l holds rterm[l]; shuffled per step
    float my_prev = BIG, my_prev2 = BIG;
    int ip = 0 - j; ip = ip < 0 ? 0 : (ip > 31 ? 31 : ip);
    float nxt_xy = cptr[(size_t)ip * cstride + j];
    for (int k = 0; k < 63; k++) {
        float cur_xy = nxt_xy;
        int in = k + 1 - j; in = in < 0 ? 0 : (in > 31 ? 31 : in);
        nxt_xy = cptr[(size_t)in * cstride + j];   // prefetch next anti-diagonal
        float lp = __shfl_up(my_prev, 1, 32);
        float dg = __shfl_up(my_prev2, 1, 32);
        if (j == 0) { lp = BIG; dg = (k == 0) ? 0.f : BIG; }
        float up = my_prev;
        int i = k - j;
        float ai = __shfl(xreg, i & 31, 32);
        float d = ai + cjv - 2.0f * cur_xy;
        float mn = fminf(dg, fminf(up, lp));
        float ssum = __expf((mn - dg) * INVG) + __expf((mn - up) * INVG) +
                     __expf((mn - lp) * INVG);
        float r = d + mn - GAMMA * __logf(ssum);
        bool active = (i >= 0) && (i < 32);
        my_prev2 = my_prev;
        my_prev = active ? r : my_prev;
    }
    if (j == 31 && valid) *outp = my_prev;  // R[31][31]
}

// ---------------- finalize: dist, log-softmax, loss, acc ----------------
__global__ __launch_bounds__(512) void finalize_kernel(const float* __restrict__ dxy,
                                                       const float* __restrict__ dxx,
                                                       const float* __restrict__ dyy,
                                                       float* __restrict__ out) {
    __shared__ float sl[512];
    __shared__ float sa[512];
    int q = threadIdx.x;
    float bl = 0.f, fl = 0.f;
    if (q < NQ) {
        float dxxq = dxx[q];
        int cq = q / NQPC;
        float dd[NCLASS];
#pragma unroll
        for (int m = 0; m < NCLASS; m++)
            dd[m] = dxy[q * NCLASS + m] - 0.5f * (dxxq + dyy[m]);
        float best = dd[0];
        int bi = 0;
#pragma unroll
        for (int m = 1; m < NCLASS; m++) {
            if (dd[m] < best) { best = dd[m]; bi = m; }
        }
        float s = 0.f;
        float dcq = dd[0];
#pragma unroll
        for (int m = 0; m < NCLASS; m++) {
            s += __expf(best - dd[m]);
            if (m == cq) dcq = dd[m];
        }
        float lse = __logf(s) - best;
        bl = dcq + lse;
        out[2 + q] = bl;
        fl = (bi == cq) ? 1.f : 0.f;
    }
    sl[threadIdx.x] = bl;
    sa[threadIdx.x] = fl;
    __syncthreads();
    for (int off = 256; off; off >>= 1) {
        if (threadIdx.x < off) {
            sl[threadIdx.x] += sl[threadIdx.x + off];
            sa[threadIdx.x] += sa[threadIdx.x + off];
        }
        __syncthreads();
    }
    if (threadIdx.x == 0) {
        out[0] = sl[0] / (float)NQ;
        out[1] = sa[0] / (float)NQ;
    }
}

extern "C" void kernel_launch(void* const* d_in, const int* in_sizes, int n_in,
                              void* d_out, int out_size, void* d_ws, size_t ws_size,
                              hipStream_t stream) {
    const float* inp = (const float*)d_in[0];
    const int* target = (const int*)d_in[1];
    float* out = (float*)d_out;
    char* ws = (char*)d_ws;

    size_t off = 0;
    auto carve = [&](size_t bytes) {
        void* p = ws + off;
        off = (off + bytes + 255) & ~(size_t)255;
        return p;
    };
    int* order = (int*)carve(NTOT * sizeof(int));
    int* qsrc = (int*)carve(NQ * sizeof(int));
    float* x2 = (float*)carve((size_t)NQROWS * sizeof(float));
    float* y2 = (float*)carve((size_t)NPROWS * sizeof(float));
    float* xy = (float*)carve((size_t)NQROWS * NPROWS * sizeof(float));  // 41 MB
    float* gxx = (float*)carve((size_t)NQ * T * T * sizeof(float));
    float* gyy = (float*)carve((size_t)NCLASS * T * T * sizeof(float));
    float* dxy = (float*)carve((size_t)NQ * NCLASS * sizeof(float));
    float* dxx = (float*)carve((size_t)NQ * sizeof(float));
    float* dyy = (float*)carve((size_t)NCLASS * sizeof(float));
    half8* Ah = (half8*)carve((size_t)(C / 8) * NQROWS * 16);  // 65.5 MB chunk-major
    half8* Bh = (half8*)carve((size_t)(C / 8) * NPROWS * 16);  // 2.6 MB (L2-resident)
    (void)ws_size;

    sort_kernel<<<1, 640, 0, stream>>>(target, order, qsrc);
    stage_kernel<<<STAGE_BLKS_A + STAGE_BLKS_B, 256, 0, stream>>>(inp, qsrc, order, Ah, Bh);
    gemm_syrk_kernel<<<SYRK_BLKS_PAD + GEMM_BLKS, 256, 0, stream>>>(Ah, Bh, xy, gxx, gyy);
    diag_kernel<<<(NQROWS + NPROWS + 255) / 256, 256, 0, stream>>>(gxx, gyy, x2, y2);
    softdtw_wave_kernel<<<(NMM + 7) / 8, 256, 0, stream>>>(xy, gxx, gyy, x2, y2, dxy, dxx, dyy);
    finalize_kernel<<<1, 512, 0, stream>>>(dxy, dxx, dyy, out);
}

// Round 18
// 178.102 us; speedup vs baseline: 1.1758x; 1.0130x over previous
//
#include <hip/hip_runtime.h>

#define T 32
#define C 2048
#define NTOT 600
#define NCLASS 20
#define NSUP 5
#define PER 30
#define NQPC 25
#define NQ 500
#define NQROWS (NQ * T)      // 16000
#define NPROWS (NCLASS * T)  // 640
#define GAMMA 0.1f
#define INVG 10.0f
#define BIG 1e10f
#define NMM (NQ * NCLASS + NQ + NCLASS)  // 10520
#define GEMM_BLKS 625
#define SYRK_BLKS_PAD 136  // multiple of 8 so gemm swizzle sees o%8 unchanged
#define SAMP_STRIDE 8192   // half8 per staged sample: 256 chunks x 32 rows
#define STAGE_BLKS_A 2400  // (600*32/16 row-tiles) x 2 col-halves
#define STAGE_BLKS_B 80    // (640/16) x 2
#define LDS_PITCH 33       // half8 per LDS row (32 chunks + 1 pad)

typedef __fp16 half8 __attribute__((ext_vector_type(8)));
typedef __fp16 half4 __attribute__((ext_vector_type(4)));
typedef float f32x4 __attribute__((ext_vector_type(4)));

// ---------------- parallel stable counting sort (1 block) ----------------
__global__ __launch_bounds__(640) void sort_kernel(const int* __restrict__ target,
                                                   int* __restrict__ order,
                                                   int* __restrict__ qsrc) {
    __shared__ int tgt[NTOT];
    __shared__ int offs[NCLASS];
    __shared__ int ordl[NTOT];
    int tid = threadIdx.x;
    if (tid < NTOT) tgt[tid] = target[tid];
    __syncthreads();
    if (tid < NCLASS) {
        int o = 0;
        for (int i = 0; i < NTOT; i++) o += (tgt[i] < tid) ? 1 : 0;
        offs[tid] = o;
    }
    __syncthreads();
    if (tid < NTOT) {
        int c = tgt[tid];
        int rank = 0;
        for (int k = 0; k < NTOT; k++) rank += (k < tid && tgt[k] == c) ? 1 : 0;
        ordl[offs[c] + rank] = tid;
    }
    __syncthreads();
    if (tid < NTOT) order[tid] = ordl[tid];
    if (tid < NQ) qsrc[tid] = ordl[(tid / NQPC) * PER + NSUP + (tid % NQPC)];
}

// ---------------- staging: sequential reads + wave-local LDS transpose ------------
// A-side: ALL 600 samples staged per-sample chunk-major Ah[s*8192 + chunk*32 + row32]
// (no gather — gemm resolves qsrc at sample level). Reads fully sequential 1KB/instr;
// writes 4x256B runs within 2KB. B-side (proto mean) unchanged: Bh[chunk*640 + row].
__global__ __launch_bounds__(256) void stage_kernel(const float* __restrict__ inp,
                                                    const int* __restrict__ order,
                                                    half8* __restrict__ Ah,
                                                    half8* __restrict__ Bh) {
    __shared__ half8 lds[4][16][LDS_PITCH];  // 33.8 KB
    int tid = threadIdx.x;
    int lane = tid & 63, w = tid >> 6;
    int bid = blockIdx.x;
    bool isA = bid < STAGE_BLKS_A;
    int b = isA ? bid : bid - STAGE_BLKS_A;
    int rowblk = b >> 1, half = b & 1;
    int row0 = rowblk * 16;
    int colbase = half * 1024 + w * 256;  // this wave's float-col window
    if (isA) {
        int sample = row0 >> 5, rowin0 = row0 & 31;  // 16-row tile within one sample
        const float* sbase = inp + (size_t)sample * (T * C) + (size_t)rowin0 * C +
                             colbase + lane * 4;
#pragma unroll
        for (int rr = 0; rr < 16; rr++) {
            float4 v = *(const float4*)(sbase + (size_t)rr * C);
            half4 hv = {(__fp16)v.x, (__fp16)v.y, (__fp16)v.z, (__fp16)v.w};
            ((half4*)&lds[w][rr][0])[lane] = hv;  // contiguous 512B per wave
        }
        __syncthreads();
        int chunkbase = half * 128 + w * 32;
        half8* dst = Ah + (size_t)sample * SAMP_STRIDE + rowin0;
#pragma unroll
        for (int c = 0; c < 8; c++) {
            int idx = c * 64 + lane;         // 0..511
            int ch = idx >> 4, row = idx & 15;
            dst[(size_t)(chunkbase + ch) * 32 + row] = lds[w][row][ch];
        }
    } else {
#pragma unroll
        for (int rr = 0; rr < 16; rr++) {
            int rg = row0 + rr;
            int cls = rg >> 5, trow = rg & 31;
            const float* base = inp + (size_t)trow * C + colbase + lane * 4;
            float4 a = *(const float4*)(base + (size_t)order[cls * PER + 0] * (T * C));
            float4 b4 = *(const float4*)(base + (size_t)order[cls * PER + 1] * (T * C));
            float4 c = *(const float4*)(base + (size_t)order[cls * PER + 2] * (T * C));
            float4 d = *(const float4*)(base + (size_t)order[cls * PER + 3] * (T * C));
            float4 e = *(const float4*)(base + (size_t)order[cls * PER + 4] * (T * C));
            float4 m;
            m.x = (a.x + b4.x + c.x + d.x + e.x) * 0.2f;
            m.y = (a.y + b4.y + c.y + d.y + e.y) * 0.2f;
            m.z = (a.z + b4.z + c.z + d.z + e.z) * 0.2f;
            m.w = (a.w + b4.w + c.w + d.w + e.w) * 0.2f;
            half4 hv = {(__fp16)m.x, (__fp16)m.y, (__fp16)m.z, (__fp16)m.w};
            ((half4*)&lds[w][rr][0])[lane] = hv;
        }
        __syncthreads();
        int chunkbase = half * 128 + w * 32;
#pragma unroll
        for (int c = 0; c < 8; c++) {
            int idx = c * 64 + lane;
            int ch = idx >> 4, row = idx & 15;
            Bh[(size_t)(chunkbase + ch) * NPROWS + row0 + row] = lds[w][row][ch];
        }
    }
}

// ---------------- merged: SYRK (blocks 0..135) + 1-term register-direct f16 GEMM --
// A per-sample chunk-major: wave's 64-row tile = exactly 2 query samples (2 bases).
// Per-instruction A loads: 4 x 256B runs inside 2KB. NO LDS, NO barriers.
__global__ __launch_bounds__(256) void gemm_syrk_kernel(const half8* __restrict__ Ah,
                                                        const half8* __restrict__ Bh,
                                                        const int* __restrict__ qsrc,
                                                        float* __restrict__ xy,
                                                        float* __restrict__ gxx,
                                                        float* __restrict__ gyy) {
    int tid = threadIdx.x, lane = tid & 63, wid = tid >> 6;
    int o = blockIdx.x;
    int g = lane >> 4, r = lane & 15;
    if (o < SYRK_BLKS_PAD) {
        // ---- SYRK path: one wave per 32x32 Gram matrix (short blocks first) ----
        int ww = o * 4 + wid;
        if (ww >= NQ + NCLASS) return;
        f32x4 acc[2][2];
        f32x4 zero = {0.f, 0.f, 0.f, 0.f};
        acc[0][0] = zero; acc[0][1] = zero; acc[1][0] = zero; acc[1][1] = zero;
        if (ww < NQ) {
            // gxx = Ah Ah^T for query sample qsrc[ww]
            const half8* p = Ah + (size_t)qsrc[ww] * SAMP_STRIDE + g * 32 + r;
            float* outp = gxx + (size_t)ww * (T * T);
            for (int t = 0; t < C / 32; t++) {
                half8 h0 = p[0], h1 = p[16];
                p += 128;  // next 4 chunks
                acc[0][0] = __builtin_amdgcn_mfma_f32_16x16x32_f16(h0, h0, acc[0][0], 0, 0, 0);
                acc[0][1] = __builtin_amdgcn_mfma_f32_16x16x32_f16(h0, h1, acc[0][1], 0, 0, 0);
                acc[1][0] = __builtin_amdgcn_mfma_f32_16x16x32_f16(h1, h0, acc[1][0], 0, 0, 0);
                acc[1][1] = __builtin_amdgcn_mfma_f32_16x16x32_f16(h1, h1, acc[1][1], 0, 0, 0);
            }
#pragma unroll
            for (int mi = 0; mi < 2; mi++)
#pragma unroll
                for (int ni = 0; ni < 2; ni++)
#pragma unroll
                    for (int j = 0; j < 4; j++)
                        outp[(mi * 16 + g * 4 + j) * T + ni * 16 + r] = acc[mi][ni][j];
        } else {
            int row0 = (ww - NQ) * 32;
            float* outp = gyy + (size_t)(ww - NQ) * (T * T);
            for (int t = 0; t < C / 32; t++) {
                size_t base = (size_t)(t * 4 + g) * NPROWS + row0 + r;
                half8 h0 = Bh[base], h1 = Bh[base + 16];
                acc[0][0] = __builtin_amdgcn_mfma_f32_16x16x32_f16(h0, h0, acc[0][0], 0, 0, 0);
                acc[0][1] = __builtin_amdgcn_mfma_f32_16x16x32_f16(h0, h1, acc[0][1], 0, 0, 0);
                acc[1][0] = __builtin_amdgcn_mfma_f32_16x16x32_f16(h1, h0, acc[1][0], 0, 0, 0);
                acc[1][1] = __builtin_amdgcn_mfma_f32_16x16x32_f16(h1, h1, acc[1][1], 0, 0, 0);
            }
#pragma unroll
            for (int mi = 0; mi < 2; mi++)
#pragma unroll
                for (int ni = 0; ni < 2; ni++)
#pragma unroll
                    for (int j = 0; j < 4; j++)
                        outp[(mi * 16 + g * 4 + j) * T + ni * 16 + r] = acc[mi][ni][j];
        }
        return;
    }
    // ---- GEMM path: xy = Ah(gathered)*Bh^T, 1 MFMA term, register-direct ----
    int oo = o - SYRK_BLKS_PAD;  // 0..624; SYRK_BLKS_PAD%8==0 keeps oo%8==o%8
    int xcd = oo & 7, slot = oo >> 3;
    int v = (xcd < 1 ? xcd * 79 : 79 + (xcd - 1) * 78) + slot;  // bijective over 625=8*78+1
    int bm = v / 5, bn = v % 5;
    int wr = wid >> 1, wc = wid & 1;
    int m0 = bm * 128 + wr * 64, n0 = bn * 128 + wc * 64;  // this wave's 64x64 tile
    int q0 = m0 >> 5;                                      // two query samples
    const half8* pA0 = Ah + (size_t)qsrc[q0] * SAMP_STRIDE + g * 32 + r;
    const half8* pA1 = Ah + (size_t)qsrc[q0 + 1] * SAMP_STRIDE + g * 32 + r;
    const half8* pB = Bh + (size_t)g * NPROWS + n0 + r;
    f32x4 acc[4][4];
    f32x4 zero = {0.f, 0.f, 0.f, 0.f};
#pragma unroll
    for (int mi = 0; mi < 4; mi++)
#pragma unroll
        for (int ni = 0; ni < 4; ni++) acc[mi][ni] = zero;
#pragma unroll 2
    for (int t = 0; t < C / 32; t++) {
        half8 ah[4], bh[4];
        ah[0] = pA0[0];   // sample q0, rows r
        ah[1] = pA0[16];  // sample q0, rows 16+r
        ah[2] = pA1[0];   // sample q0+1
        ah[3] = pA1[16];
#pragma unroll
        for (int i = 0; i < 4; i++) bh[i] = pB[i * 16];
        pA0 += 128;
        pA1 += 128;
        pB += 4 * NPROWS;
#pragma unroll
        for (int mi = 0; mi < 4; mi++)
#pragma unroll
            for (int ni = 0; ni < 4; ni++)
                acc[mi][ni] = __builtin_amdgcn_mfma_f32_16x16x32_f16(ah[mi], bh[ni], acc[mi][ni], 0, 0, 0);
    }
    int orow = m0 + g * 4;
    int ocol = n0 + r;
#pragma unroll
    for (int mi = 0; mi < 4; mi++)
#pragma unroll
        for (int ni = 0; ni < 4; ni++)
#pragma unroll
            for (int j = 0; j < 4; j++)
                xy[(size_t)(orow + mi * 16 + j) * NPROWS + ocol + ni * 16] = acc[mi][ni][j];
}

// ---------------- extract row norms from Gram diagonals ----------------
__global__ void diag_kernel(const float* __restrict__ gxx, const float* __restrict__ gyy,
                            float* __restrict__ x2, float* __restrict__ y2) {
    int i = blockIdx.x * 256 + threadIdx.x;
    if (i < NQROWS) {
        x2[i] = gxx[(size_t)(i >> 5) * (T * T) + (i & 31) * (T + 1)];
    } else if (i < NQROWS + NPROWS) {
        int j = i - NQROWS;
        y2[j] = gyy[(size_t)(j >> 5) * (T * T) + (j & 31) * (T + 1)];
    }
}

// ---------------- wavefront soft-DTW: 32 lanes = 32 columns, 2 matrices/wave ------
__global__ __launch_bounds__(256) void softdtw_wave_kernel(
        const float* __restrict__ xy, const float* __restrict__ gxx,
        const float* __restrict__ gyy, const float* __restrict__ x2,
        const float* __restrict__ y2, float* __restrict__ dxy,
        float* __restrict__ dxx, float* __restrict__ dyy) {
    int tid = threadIdx.x;
    int j = tid & 31;                       // column within the matrix
    int mm = blockIdx.x * 8 + (tid >> 5);   // 8 matrices per 256-thread block
    bool valid = mm < NMM;
    int mmc = valid ? mm : 0;
    const float* rterm;
    const float* cterm;
    const float* cptr;
    int cstride;
    float* outp;
    if (mmc < NQ * NCLASS) {
        int q = mmc / NCLASS, m = mmc % NCLASS;
        rterm = x2 + q * T;
        cterm = y2 + m * T;
        cptr = xy + (size_t)(q * T) * NPROWS + m * T;
        cstride = NPROWS;
        outp = dxy + mmc;
    } else if (mmc < NQ * NCLASS + NQ) {
        int i = mmc - NQ * NCLASS;
        rterm = x2 + i * T;
        cterm = rterm;
        cptr = gxx + (size_t)i * (T * T);
        cstride = T;
        outp = dxx + i;
    } else {
        int i = mmc - NQ * NCLASS - NQ;
        rterm = y2 + i * T;
        cterm = rterm;
        cptr = gyy + (size_t)i * (T * T);
        cstride = T;
        outp = dyy + i;
    }
    float cjv = cterm[j];      // column term (lane-resident)
    float xreg = rterm[j];     // lane l holds rterm[l]; shuffled per step
    float my_prev = BIG, my_prev2 = BIG;
    int ip = 0 - j; ip = ip < 0 ? 0 : (ip > 31 ? 31 : ip);
    float nxt_xy = cptr[(size_t)ip * cstride + j];
    for (int k = 0; k < 63; k++) {
        float cur_xy = nxt_xy;
        int in = k + 1 - j; in = in < 0 ? 0 : (in > 31 ? 31 : in);
        nxt_xy = cptr[(size_t)in * cstride + j];   // prefetch next anti-diagonal
        float lp = __shfl_up(my_prev, 1, 32);
        float dg = __shfl_up(my_prev2, 1, 32);
        if (j == 0) { lp = BIG; dg = (k == 0) ? 0.f : BIG; }
        float up = my_prev;
        int i = k - j;
        float ai = __shfl(xreg, i & 31, 32);
        float d = ai + cjv - 2.0f * cur_xy;
        float mn = fminf(dg, fminf(up, lp));
        float ssum = __expf((mn - dg) * INVG) + __expf((mn - up) * INVG) +
                     __expf((mn - lp) * INVG);
        float r = d + mn - GAMMA * __logf(ssum);
        bool active = (i >= 0) && (i < 32);
        my_prev2 = my_prev;
        my_prev = active ? r : my_prev;
    }
    if (j == 31 && valid) *outp = my_prev;  // R[31][31]
}

// ---------------- finalize: dist, log-softmax, loss, acc ----------------
__global__ __launch_bounds__(512) void finalize_kernel(const float* __restrict__ dxy,
                                                       const float* __restrict__ dxx,
                                                       const float* __restrict__ dyy,
                                                       float* __restrict__ out) {
    __shared__ float sl[512];
    __shared__ float sa[512];
    int q = threadIdx.x;
    float bl = 0.f, fl = 0.f;
    if (q < NQ) {
        float dxxq = dxx[q];
        int cq = q / NQPC;
        float dd[NCLASS];
#pragma unroll
        for (int m = 0; m < NCLASS; m++)
            dd[m] = dxy[q * NCLASS + m] - 0.5f * (dxxq + dyy[m]);
        float best = dd[0];
        int bi = 0;
#pragma unroll
        for (int m = 1; m < NCLASS; m++) {
            if (dd[m] < best) { best = dd[m]; bi = m; }
        }
        float s = 0.f;
        float dcq = dd[0];
#pragma unroll
        for (int m = 0; m < NCLASS; m++) {
            s += __expf(best - dd[m]);
            if (m == cq) dcq = dd[m];
        }
        float lse = __logf(s) - best;
        bl = dcq + lse;
        out[2 + q] = bl;
        fl = (bi == cq) ? 1.f : 0.f;
    }
    sl[threadIdx.x] = bl;
    sa[threadIdx.x] = fl;
    __syncthreads();
    for (int off = 256; off; off >>= 1) {
        if (threadIdx.x < off) {
            sl[threadIdx.x] += sl[threadIdx.x + off];
            sa[threadIdx.x] += sa[threadIdx.x + off];
        }
        __syncthreads();
    }
    if (threadIdx.x == 0) {
        out[0] = sl[0] / (float)NQ;
        out[1] = sa[0] / (float)NQ;
    }
}

extern "C" void kernel_launch(void* const* d_in, const int* in_sizes, int n_in,
                              void* d_out, int out_size, void* d_ws, size_t ws_size,
                              hipStream_t stream) {
    const float* inp = (const float*)d_in[0];
    const int* target = (const int*)d_in[1];
    float* out = (float*)d_out;
    char* ws = (char*)d_ws;

    size_t off = 0;
    auto carve = [&](size_t bytes) {
        void* p = ws + off;
        off = (off + bytes + 255) & ~(size_t)255;
        return p;
    };
    int* order = (int*)carve(NTOT * sizeof(int));
    int* qsrc = (int*)carve(NQ * sizeof(int));
    float* x2 = (float*)carve((size_t)NQROWS * sizeof(float));
    float* y2 = (float*)carve((size_t)NPROWS * sizeof(float));
    float* xy = (float*)carve((size_t)NQROWS * NPROWS * sizeof(float));  // 41 MB
    float* gxx = (float*)carve((size_t)NQ * T * T * sizeof(float));
    float* gyy = (float*)carve((size_t)NCLASS * T * T * sizeof(float));
    float* dxy = (float*)carve((size_t)NQ * NCLASS * sizeof(float));
    float* dxx = (float*)carve((size_t)NQ * sizeof(float));
    float* dyy = (float*)carve((size_t)NCLASS * sizeof(float));
    half8* Ah = (half8*)carve((size_t)NTOT * SAMP_STRIDE * 16);  // 78.6 MB per-sample
    half8* Bh = (half8*)carve((size_t)(C / 8) * NPROWS * 16);    // 2.6 MB (L2-resident)
    (void)ws_size;

    sort_kernel<<<1, 640, 0, stream>>>(target, order, qsrc);
    stage_kernel<<<STAGE_BLKS_A + STAGE_BLKS_B, 256, 0, stream>>>(inp, order, Ah, Bh);
    gemm_syrk_kernel<<<SYRK_BLKS_PAD + GEMM_BLKS, 256, 0, stream>>>(Ah, Bh, qsrc, xy, gxx, gyy);
    diag_kernel<<<(NQROWS + NPROWS + 255) / 256, 256, 0, stream>>>(gxx, gyy, x2, y2);
    softdtw_wave_kernel<<<(NMM + 7) / 8, 256, 0, stream>>>(xy, gxx, gyy, x2, y2, dxy, dxx, dyy);
    finalize_kernel<<<1, 512, 0, stream>>>(dxy, dxx, dyy, out);
}

// Round 19
// 173.901 us; speedup vs baseline: 1.2042x; 1.0242x over previous
//
#include <hip/hip_runtime.h>

#define T 32
#define C 2048
#define NTOT 600
#define NCLASS 20
#define NSUP 5
#define PER 30
#define NQPC 25
#define NQ 500
#define NQROWS (NQ * T)      // 16000
#define NPROWS (NCLASS * T)  // 640
#define GAMMA 0.1f
#define INVG 10.0f
#define BIG 1e10f
#define NMM (NQ * NCLASS + NQ + NCLASS)  // 10520
#define GEMM_BLKS 625
#define SYRK_BLKS_PAD 136  // multiple of 8 so gemm swizzle sees o%8 unchanged
#define SAMP_STRIDE 8192   // half8 per staged query sample: 256 chunks x 32 rows
#define STAGE_BLKS_A 2000  // (500*32/16 row-tiles) x 2 col-halves
#define STAGE_BLKS_B 80    // (640/16) x 2
#define LDS_PITCH 33       // half8 per LDS row (32 chunks + 1 pad)

typedef __fp16 half8 __attribute__((ext_vector_type(8)));
typedef __fp16 half4 __attribute__((ext_vector_type(4)));
typedef float f32x4 __attribute__((ext_vector_type(4)));

// ---------------- parallel stable counting sort (1 block) ----------------
__global__ __launch_bounds__(640) void sort_kernel(const int* __restrict__ target,
                                                   int* __restrict__ order,
                                                   int* __restrict__ qsrc) {
    __shared__ int tgt[NTOT];
    __shared__ int offs[NCLASS];
    __shared__ int ordl[NTOT];
    int tid = threadIdx.x;
    if (tid < NTOT) tgt[tid] = target[tid];
    __syncthreads();
    if (tid < NCLASS) {
        int o = 0;
        for (int i = 0; i < NTOT; i++) o += (tgt[i] < tid) ? 1 : 0;
        offs[tid] = o;
    }
    __syncthreads();
    if (tid < NTOT) {
        int c = tgt[tid];
        int rank = 0;
        for (int k = 0; k < NTOT; k++) rank += (k < tid && tgt[k] == c) ? 1 : 0;
        ordl[offs[c] + rank] = tid;
    }
    __syncthreads();
    if (tid < NTOT) order[tid] = ordl[tid];
    if (tid < NQ) qsrc[tid] = ordl[(tid / NQPC) * PER + NSUP + (tid % NQPC)];
}

// ---------------- staging: query-only gather + wave-local LDS transpose -----------
// A-side: the 500 QUERY samples staged per-query chunk-major
// Ah[q*8192 + chunk*32 + row32] (sample-level gather; within-tile reads are 1KB
// coalesced per instr). Writes 4x256B runs within 2KB. B-side: Bh[chunk*640 + row].
__global__ __launch_bounds__(256) void stage_kernel(const float* __restrict__ inp,
                                                    const int* __restrict__ qsrc,
                                                    const int* __restrict__ order,
                                                    half8* __restrict__ Ah,
                                                    half8* __restrict__ Bh) {
    __shared__ half8 lds[4][16][LDS_PITCH];  // 33.8 KB
    int tid = threadIdx.x;
    int lane = tid & 63, w = tid >> 6;
    int bid = blockIdx.x;
    bool isA = bid < STAGE_BLKS_A;
    int b = isA ? bid : bid - STAGE_BLKS_A;
    int rowblk = b >> 1, half = b & 1;
    int row0 = rowblk * 16;
    int colbase = half * 1024 + w * 256;  // this wave's float-col window
    if (isA) {
        int q = row0 >> 5, rowin0 = row0 & 31;  // 16-row tile within one query sample
        const float* sbase = inp + (size_t)qsrc[q] * (T * C) + (size_t)rowin0 * C +
                             colbase + lane * 4;
#pragma unroll
        for (int rr = 0; rr < 16; rr++) {
            float4 v = *(const float4*)(sbase + (size_t)rr * C);
            half4 hv = {(__fp16)v.x, (__fp16)v.y, (__fp16)v.z, (__fp16)v.w};
            ((half4*)&lds[w][rr][0])[lane] = hv;  // contiguous 512B per wave
        }
        __syncthreads();
        int chunkbase = half * 128 + w * 32;
        half8* dst = Ah + (size_t)q * SAMP_STRIDE + rowin0;
#pragma unroll
        for (int c = 0; c < 8; c++) {
            int idx = c * 64 + lane;         // 0..511
            int ch = idx >> 4, row = idx & 15;
            dst[(size_t)(chunkbase + ch) * 32 + row] = lds[w][row][ch];
        }
    } else {
#pragma unroll
        for (int rr = 0; rr < 16; rr++) {
            int rg = row0 + rr;
            int cls = rg >> 5, trow = rg & 31;
            const float* base = inp + (size_t)trow * C + colbase + lane * 4;
            float4 a = *(const float4*)(base + (size_t)order[cls * PER + 0] * (T * C));
            float4 b4 = *(const float4*)(base + (size_t)order[cls * PER + 1] * (T * C));
            float4 c = *(const float4*)(base + (size_t)order[cls * PER + 2] * (T * C));
            float4 d = *(const float4*)(base + (size_t)order[cls * PER + 3] * (T * C));
            float4 e = *(const float4*)(base + (size_t)order[cls * PER + 4] * (T * C));
            float4 m;
            m.x = (a.x + b4.x + c.x + d.x + e.x) * 0.2f;
            m.y = (a.y + b4.y + c.y + d.y + e.y) * 0.2f;
            m.z = (a.z + b4.z + c.z + d.z + e.z) * 0.2f;
            m.w = (a.w + b4.w + c.w + d.w + e.w) * 0.2f;
            half4 hv = {(__fp16)m.x, (__fp16)m.y, (__fp16)m.z, (__fp16)m.w};
            ((half4*)&lds[w][rr][0])[lane] = hv;
        }
        __syncthreads();
        int chunkbase = half * 128 + w * 32;
#pragma unroll
        for (int c = 0; c < 8; c++) {
            int idx = c * 64 + lane;
            int ch = idx >> 4, row = idx & 15;
            Bh[(size_t)(chunkbase + ch) * NPROWS + row0 + row] = lds[w][row][ch];
        }
    }
}

// ---------------- merged: SYRK (blocks 0..135) + 1-term register-direct f16 GEMM --
// Ah indexed by query id (no indirection). Per-instr A loads: 4 x 256B runs in 2KB.
// NO LDS, NO barriers (R10/R15 schedule).
__global__ __launch_bounds__(256) void gemm_syrk_kernel(const half8* __restrict__ Ah,
                                                        const half8* __restrict__ Bh,
                                                        float* __restrict__ xy,
                                                        float* __restrict__ gxx,
                                                        float* __restrict__ gyy) {
    int tid = threadIdx.x, lane = tid & 63, wid = tid >> 6;
    int o = blockIdx.x;
    int g = lane >> 4, r = lane & 15;
    if (o < SYRK_BLKS_PAD) {
        // ---- SYRK path: one wave per 32x32 Gram matrix (short blocks first) ----
        int ww = o * 4 + wid;
        if (ww >= NQ + NCLASS) return;
        f32x4 acc[2][2];
        f32x4 zero = {0.f, 0.f, 0.f, 0.f};
        acc[0][0] = zero; acc[0][1] = zero; acc[1][0] = zero; acc[1][1] = zero;
        if (ww < NQ) {
            // gxx = Ah Ah^T for query ww
            const half8* p = Ah + (size_t)ww * SAMP_STRIDE + g * 32 + r;
            float* outp = gxx + (size_t)ww * (T * T);
            for (int t = 0; t < C / 32; t++) {
                half8 h0 = p[0], h1 = p[16];
                p += 128;  // next 4 chunks
                acc[0][0] = __builtin_amdgcn_mfma_f32_16x16x32_f16(h0, h0, acc[0][0], 0, 0, 0);
                acc[0][1] = __builtin_amdgcn_mfma_f32_16x16x32_f16(h0, h1, acc[0][1], 0, 0, 0);
                acc[1][0] = __builtin_amdgcn_mfma_f32_16x16x32_f16(h1, h0, acc[1][0], 0, 0, 0);
                acc[1][1] = __builtin_amdgcn_mfma_f32_16x16x32_f16(h1, h1, acc[1][1], 0, 0, 0);
            }
#pragma unroll
            for (int mi = 0; mi < 2; mi++)
#pragma unroll
                for (int ni = 0; ni < 2; ni++)
#pragma unroll
                    for (int j = 0; j < 4; j++)
                        outp[(mi * 16 + g * 4 + j) * T + ni * 16 + r] = acc[mi][ni][j];
        } else {
            int row0 = (ww - NQ) * 32;
            float* outp = gyy + (size_t)(ww - NQ) * (T * T);
            for (int t = 0; t < C / 32; t++) {
                size_t base = (size_t)(t * 4 + g) * NPROWS + row0 + r;
                half8 h0 = Bh[base], h1 = Bh[base + 16];
                acc[0][0] = __builtin_amdgcn_mfma_f32_16x16x32_f16(h0, h0, acc[0][0], 0, 0, 0);
                acc[0][1] = __builtin_amdgcn_mfma_f32_16x16x32_f16(h0, h1, acc[0][1], 0, 0, 0);
                acc[1][0] = __builtin_amdgcn_mfma_f32_16x16x32_f16(h1, h0, acc[1][0], 0, 0, 0);
                acc[1][1] = __builtin_amdgcn_mfma_f32_16x16x32_f16(h1, h1, acc[1][1], 0, 0, 0);
            }
#pragma unroll
            for (int mi = 0; mi < 2; mi++)
#pragma unroll
                for (int ni = 0; ni < 2; ni++)
#pragma unroll
                    for (int j = 0; j < 4; j++)
                        outp[(mi * 16 + g * 4 + j) * T + ni * 16 + r] = acc[mi][ni][j];
        }
        return;
    }
    // ---- GEMM path: xy = Ah*Bh^T, 1 MFMA term, register-direct ----
    int oo = o - SYRK_BLKS_PAD;  // 0..624; SYRK_BLKS_PAD%8==0 keeps oo%8==o%8
    int xcd = oo & 7, slot = oo >> 3;
    int v = (xcd < 1 ? xcd * 79 : 79 + (xcd - 1) * 78) + slot;  // bijective over 625=8*78+1
    int bm = v / 5, bn = v % 5;
    int wr = wid >> 1, wc = wid & 1;
    int m0 = bm * 128 + wr * 64, n0 = bn * 128 + wc * 64;  // this wave's 64x64 tile
    int q0 = m0 >> 5;                                      // two query samples
    const half8* pA0 = Ah + (size_t)q0 * SAMP_STRIDE + g * 32 + r;
    const half8* pA1 = pA0 + SAMP_STRIDE;
    const half8* pB = Bh + (size_t)g * NPROWS + n0 + r;
    f32x4 acc[4][4];
    f32x4 zero = {0.f, 0.f, 0.f, 0.f};
#pragma unroll
    for (int mi = 0; mi < 4; mi++)
#pragma unroll
        for (int ni = 0; ni < 4; ni++) acc[mi][ni] = zero;
#pragma unroll 2
    for (int t = 0; t < C / 32; t++) {
        half8 ah[4], bh[4];
        ah[0] = pA0[0];   // query q0, rows r
        ah[1] = pA0[16];  // query q0, rows 16+r
        ah[2] = pA1[0];   // query q0+1
        ah[3] = pA1[16];
#pragma unroll
        for (int i = 0; i < 4; i++) bh[i] = pB[i * 16];
        pA0 += 128;
        pA1 += 128;
        pB += 4 * NPROWS;
#pragma unroll
        for (int mi = 0; mi < 4; mi++)
#pragma unroll
            for (int ni = 0; ni < 4; ni++)
                acc[mi][ni] = __builtin_amdgcn_mfma_f32_16x16x32_f16(ah[mi], bh[ni], acc[mi][ni], 0, 0, 0);
    }
    int orow = m0 + g * 4;
    int ocol = n0 + r;
#pragma unroll
    for (int mi = 0; mi < 4; mi++)
#pragma unroll
        for (int ni = 0; ni < 4; ni++)
#pragma unroll
            for (int j = 0; j < 4; j++)
                xy[(size_t)(orow + mi * 16 + j) * NPROWS + ocol + ni * 16] = acc[mi][ni][j];
}

// ---------------- wavefront soft-DTW: reads Gram diagonals directly ---------------
// rterm_j = gxx[q][j][j], cterm_j = gyy[m][j][j] (strided L2-hit loads, once/matrix).
__global__ __launch_bounds__(256) void softdtw_wave_kernel(
        const float* __restrict__ xy, const float* __restrict__ gxx,
        const float* __restrict__ gyy, float* __restrict__ dxy,
        float* __restrict__ dxx, float* __restrict__ dyy) {
    int tid = threadIdx.x;
    int j = tid & 31;                       // column within the matrix
    int mm = blockIdx.x * 8 + (tid >> 5);   // 8 matrices per 256-thread block
    bool valid = mm < NMM;
    int mmc = valid ? mm : 0;
    const float* rbase;
    const float* cbase;
    const float* cptr;
    int cstride;
    float* outp;
    if (mmc < NQ * NCLASS) {
        int q = mmc / NCLASS, m = mmc % NCLASS;
        rbase = gxx + (size_t)q * (T * T);
        cbase = gyy + (size_t)m * (T * T);
        cptr = xy + (size_t)(q * T) * NPROWS + m * T;
        cstride = NPROWS;
        outp = dxy + mmc;
    } else if (mmc < NQ * NCLASS + NQ) {
        int i = mmc - NQ * NCLASS;
        rbase = gxx + (size_t)i * (T * T);
        cbase = rbase;
        cptr = rbase;
        cstride = T;
        outp = dxx + i;
    } else {
        int i = mmc - NQ * NCLASS - NQ;
        rbase = gyy + (size_t)i * (T * T);
        cbase = rbase;
        cptr = rbase;
        cstride = T;
        outp = dyy + i;
    }
    float cjv = cbase[j * 33];  // diag element (j,j)
    float xreg = rbase[j * 33]; // lane l holds rterm[l]; shuffled per step
    float my_prev = BIG, my_prev2 = BIG;
    int ip = 0 - j; ip = ip < 0 ? 0 : (ip > 31 ? 31 : ip);
    float nxt_xy = cptr[(size_t)ip * cstride + j];
    for (int k = 0; k < 63; k++) {
        float cur_xy = nxt_xy;
        int in = k + 1 - j; in = in < 0 ? 0 : (in > 31 ? 31 : in);
        nxt_xy = cptr[(size_t)in * cstride + j];   // prefetch next anti-diagonal
        float lp = __shfl_up(my_prev, 1, 32);
        float dg = __shfl_up(my_prev2, 1, 32);
        if (j == 0) { lp = BIG; dg = (k == 0) ? 0.f : BIG; }
        float up = my_prev;
        int i = k - j;
        float ai = __shfl(xreg, i & 31, 32);
        float d = ai + cjv - 2.0f * cur_xy;
        float mn = fminf(dg, fminf(up, lp));
        float ssum = __expf((mn - dg) * INVG) + __expf((mn - up) * INVG) +
                     __expf((mn - lp) * INVG);
        float r = d + mn - GAMMA * __logf(ssum);
        bool active = (i >= 0) && (i < 32);
        my_prev2 = my_prev;
        my_prev = active ? r : my_prev;
    }
    if (j == 31 && valid) *outp = my_prev;  // R[31][31]
}

// ---------------- finalize: dist, log-softmax, loss, acc ----------------
__global__ __launch_bounds__(512) void finalize_kernel(const float* __restrict__ dxy,
                                                       const float* __restrict__ dxx,
                                                       const float* __restrict__ dyy,
                                                       float* __restrict__ out) {
    __shared__ float sl[512];
    __shared__ float sa[512];
    int q = threadIdx.x;
    float bl = 0.f, fl = 0.f;
    if (q < NQ) {
        float dxxq = dxx[q];
        int cq = q / NQPC;
        float dd[NCLASS];
#pragma unroll
        for (int m = 0; m < NCLASS; m++)
            dd[m] = dxy[q * NCLASS + m] - 0.5f * (dxxq + dyy[m]);
        float best = dd[0];
        int bi = 0;
#pragma unroll
        for (int m = 1; m < NCLASS; m++) {
            if (dd[m] < best) { best = dd[m]; bi = m; }
        }
        float s = 0.f;
        float dcq = dd[0];
#pragma unroll
        for (int m = 0; m < NCLASS; m++) {
            s += __expf(best - dd[m]);
            if (m == cq) dcq = dd[m];
        }
        float lse = __logf(s) - best;
        bl = dcq + lse;
        out[2 + q] = bl;
        fl = (bi == cq) ? 1.f : 0.f;
    }
    sl[threadIdx.x] = bl;
    sa[threadIdx.x] = fl;
    __syncthreads();
    for (int off = 256; off; off >>= 1) {
        if (threadIdx.x < off) {
            sl[threadIdx.x] += sl[threadIdx.x + off];
            sa[threadIdx.x] += sa[threadIdx.x + off];
        }
        __syncthreads();
    }
    if (threadIdx.x == 0) {
        out[0] = sl[0] / (float)NQ;
        out[1] = sa[0] / (float)NQ;
    }
}

extern "C" void kernel_launch(void* const* d_in, const int* in_sizes, int n_in,
                              void* d_out, int out_size, void* d_ws, size_t ws_size,
                              hipStream_t stream) {
    const float* inp = (const float*)d_in[0];
    const int* target = (const int*)d_in[1];
    float* out = (float*)d_out;
    char* ws = (char*)d_ws;

    size_t off = 0;
    auto carve = [&](size_t bytes) {
        void* p = ws + off;
        off = (off + bytes + 255) & ~(size_t)255;
        return p;
    };
    int* order = (int*)carve(NTOT * sizeof(int));
    int* qsrc = (int*)carve(NQ * sizeof(int));
    float* xy = (float*)carve((size_t)NQROWS * NPROWS * sizeof(float));  // 41 MB
    float* gxx = (float*)carve((size_t)NQ * T * T * sizeof(float));
    float* gyy = (float*)carve((size_t)NCLASS * T * T * sizeof(float));
    float* dxy = (float*)carve((size_t)NQ * NCLASS * sizeof(float));
    float* dxx = (float*)carve((size_t)NQ * sizeof(float));
    float* dyy = (float*)carve((size_t)NCLASS * sizeof(float));
    half8* Ah = (half8*)carve((size_t)NQ * SAMP_STRIDE * 16);  // 65.5 MB per-query
    half8* Bh = (half8*)carve((size_t)(C / 8) * NPROWS * 16);  // 2.6 MB (L2-resident)
    (void)ws_size;

    sort_kernel<<<1, 640, 0, stream>>>(target, order, qsrc);
    stage_kernel<<<STAGE_BLKS_A + STAGE_BLKS_B, 256, 0, stream>>>(inp, qsrc, order, Ah, Bh);
    gemm_syrk_kernel<<<SYRK_BLKS_PAD + GEMM_BLKS, 256, 0, stream>>>(Ah, Bh, xy, gxx, gyy);
    softdtw_wave_kernel<<<(NMM + 7) / 8, 256, 0, stream>>>(xy, gxx, gyy, dxy, dxx, dyy);
    finalize_kernel<<<1, 512, 0, stream>>>(dxy, dxx, dyy, out);
}

// Round 20
// 171.995 us; speedup vs baseline: 1.2175x; 1.0111x over previous
//
#include <hip/hip_runtime.h>

#define T 32
#define C 2048
#define NTOT 600
#define NCLASS 20
#define NSUP 5
#define PER 30
#define NQPC 25
#define NQ 500
#define NQROWS (NQ * T)      // 16000
#define NPROWS (NCLASS * T)  // 640
#define GAMMA 0.1f
#define INVG 10.0f
#define BIG 1e10f
#define NMM (NQ * NCLASS + NQ + NCLASS)  // 10520
#define GEMM_BLKS 625
#define SYRK_BLKS_PAD 136  // multiple of 8 so gemm swizzle sees o%8 unchanged
#define SAMP_STRIDE 8192   // half8 per staged query sample: 256 chunks x 32 rows
#define STAGE_BLKS_A 2000  // (500*32/16 row-tiles) x 2 col-halves
#define STAGE_BLKS_B 80    // (640/16) x 2
#define LDS_PITCH 33       // half8 per LDS row (32 chunks + 1 pad)

typedef __fp16 half8 __attribute__((ext_vector_type(8)));
typedef __fp16 half4 __attribute__((ext_vector_type(4)));
typedef float f32x4 __attribute__((ext_vector_type(4)));

// ---------------- parallel stable counting sort (1 block) ----------------
__global__ __launch_bounds__(640) void sort_kernel(const int* __restrict__ target,
                                                   int* __restrict__ order,
                                                   int* __restrict__ qsrc) {
    __shared__ int tgt[NTOT];
    __shared__ int offs[NCLASS];
    __shared__ int ordl[NTOT];
    int tid = threadIdx.x;
    if (tid < NTOT) tgt[tid] = target[tid];
    __syncthreads();
    if (tid < NCLASS) {
        int o = 0;
        for (int i = 0; i < NTOT; i++) o += (tgt[i] < tid) ? 1 : 0;
        offs[tid] = o;
    }
    __syncthreads();
    if (tid < NTOT) {
        int c = tgt[tid];
        int rank = 0;
        for (int k = 0; k < NTOT; k++) rank += (k < tid && tgt[k] == c) ? 1 : 0;
        ordl[offs[c] + rank] = tid;
    }
    __syncthreads();
    if (tid < NTOT) order[tid] = ordl[tid];
    if (tid < NQ) qsrc[tid] = ordl[(tid / NQPC) * PER + NSUP + (tid % NQPC)];
}

// ---------------- staging: query-only gather + wave-local LDS transpose -----------
__global__ __launch_bounds__(256) void stage_kernel(const float* __restrict__ inp,
                                                    const int* __restrict__ qsrc,
                                                    const int* __restrict__ order,
                                                    half8* __restrict__ Ah,
                                                    half8* __restrict__ Bh) {
    __shared__ half8 lds[4][16][LDS_PITCH];  // 33.8 KB
    int tid = threadIdx.x;
    int lane = tid & 63, w = tid >> 6;
    int bid = blockIdx.x;
    bool isA = bid < STAGE_BLKS_A;
    int b = isA ? bid : bid - STAGE_BLKS_A;
    int rowblk = b >> 1, half = b & 1;
    int row0 = rowblk * 16;
    int colbase = half * 1024 + w * 256;  // this wave's float-col window
    if (isA) {
        int q = row0 >> 5, rowin0 = row0 & 31;  // 16-row tile within one query sample
        const float* sbase = inp + (size_t)qsrc[q] * (T * C) + (size_t)rowin0 * C +
                             colbase + lane * 4;
#pragma unroll
        for (int rr = 0; rr < 16; rr++) {
            float4 v = *(const float4*)(sbase + (size_t)rr * C);
            half4 hv = {(__fp16)v.x, (__fp16)v.y, (__fp16)v.z, (__fp16)v.w};
            ((half4*)&lds[w][rr][0])[lane] = hv;  // contiguous 512B per wave
        }
        __syncthreads();
        int chunkbase = half * 128 + w * 32;
        half8* dst = Ah + (size_t)q * SAMP_STRIDE + rowin0;
#pragma unroll
        for (int c = 0; c < 8; c++) {
            int idx = c * 64 + lane;         // 0..511
            int ch = idx >> 4, row = idx & 15;
            dst[(size_t)(chunkbase + ch) * 32 + row] = lds[w][row][ch];
        }
    } else {
#pragma unroll
        for (int rr = 0; rr < 16; rr++) {
            int rg = row0 + rr;
            int cls = rg >> 5, trow = rg & 31;
            const float* base = inp + (size_t)trow * C + colbase + lane * 4;
            float4 a = *(const float4*)(base + (size_t)order[cls * PER + 0] * (T * C));
            float4 b4 = *(const float4*)(base + (size_t)order[cls * PER + 1] * (T * C));
            float4 c = *(const float4*)(base + (size_t)order[cls * PER + 2] * (T * C));
            float4 d = *(const float4*)(base + (size_t)order[cls * PER + 3] * (T * C));
            float4 e = *(const float4*)(base + (size_t)order[cls * PER + 4] * (T * C));
            float4 m;
            m.x = (a.x + b4.x + c.x + d.x + e.x) * 0.2f;
            m.y = (a.y + b4.y + c.y + d.y + e.y) * 0.2f;
            m.z = (a.z + b4.z + c.z + d.z + e.z) * 0.2f;
            m.w = (a.w + b4.w + c.w + d.w + e.w) * 0.2f;
            half4 hv = {(__fp16)m.x, (__fp16)m.y, (__fp16)m.z, (__fp16)m.w};
            ((half4*)&lds[w][rr][0])[lane] = hv;
        }
        __syncthreads();
        int chunkbase = half * 128 + w * 32;
#pragma unroll
        for (int c = 0; c < 8; c++) {
            int idx = c * 64 + lane;
            int ch = idx >> 4, row = idx & 15;
            Bh[(size_t)(chunkbase + ch) * NPROWS + row0 + row] = lds[w][row][ch];
        }
    }
}

// ---------------- merged: SYRK (blocks 0..135) + 1-term register-direct f16 GEMM --
// xy output is BLOCKED: xy[(q*NCLASS+m)*1024 + rin*32 + cin] — each (q,m) cost
// matrix is 4KB contiguous (same stride-32 form as gxx/gyy).
__global__ __launch_bounds__(256) void gemm_syrk_kernel(const half8* __restrict__ Ah,
                                                        const half8* __restrict__ Bh,
                                                        float* __restrict__ xy,
                                                        float* __restrict__ gxx,
                                                        float* __restrict__ gyy) {
    int tid = threadIdx.x, lane = tid & 63, wid = tid >> 6;
    int o = blockIdx.x;
    int g = lane >> 4, r = lane & 15;
    if (o < SYRK_BLKS_PAD) {
        // ---- SYRK path: one wave per 32x32 Gram matrix (short blocks first) ----
        int ww = o * 4 + wid;
        if (ww >= NQ + NCLASS) return;
        f32x4 acc[2][2];
        f32x4 zero = {0.f, 0.f, 0.f, 0.f};
        acc[0][0] = zero; acc[0][1] = zero; acc[1][0] = zero; acc[1][1] = zero;
        if (ww < NQ) {
            // gxx = Ah Ah^T for query ww
            const half8* p = Ah + (size_t)ww * SAMP_STRIDE + g * 32 + r;
            float* outp = gxx + (size_t)ww * (T * T);
            for (int t = 0; t < C / 32; t++) {
                half8 h0 = p[0], h1 = p[16];
                p += 128;  // next 4 chunks
                acc[0][0] = __builtin_amdgcn_mfma_f32_16x16x32_f16(h0, h0, acc[0][0], 0, 0, 0);
                acc[0][1] = __builtin_amdgcn_mfma_f32_16x16x32_f16(h0, h1, acc[0][1], 0, 0, 0);
                acc[1][0] = __builtin_amdgcn_mfma_f32_16x16x32_f16(h1, h0, acc[1][0], 0, 0, 0);
                acc[1][1] = __builtin_amdgcn_mfma_f32_16x16x32_f16(h1, h1, acc[1][1], 0, 0, 0);
            }
#pragma unroll
            for (int mi = 0; mi < 2; mi++)
#pragma unroll
                for (int ni = 0; ni < 2; ni++)
#pragma unroll
                    for (int j = 0; j < 4; j++)
                        outp[(mi * 16 + g * 4 + j) * T + ni * 16 + r] = acc[mi][ni][j];
        } else {
            int row0 = (ww - NQ) * 32;
            float* outp = gyy + (size_t)(ww - NQ) * (T * T);
            for (int t = 0; t < C / 32; t++) {
                size_t base = (size_t)(t * 4 + g) * NPROWS + row0 + r;
                half8 h0 = Bh[base], h1 = Bh[base + 16];
                acc[0][0] = __builtin_amdgcn_mfma_f32_16x16x32_f16(h0, h0, acc[0][0], 0, 0, 0);
                acc[0][1] = __builtin_amdgcn_mfma_f32_16x16x32_f16(h0, h1, acc[0][1], 0, 0, 0);
                acc[1][0] = __builtin_amdgcn_mfma_f32_16x16x32_f16(h1, h0, acc[1][0], 0, 0, 0);
                acc[1][1] = __builtin_amdgcn_mfma_f32_16x16x32_f16(h1, h1, acc[1][1], 0, 0, 0);
            }
#pragma unroll
            for (int mi = 0; mi < 2; mi++)
#pragma unroll
                for (int ni = 0; ni < 2; ni++)
#pragma unroll
                    for (int j = 0; j < 4; j++)
                        outp[(mi * 16 + g * 4 + j) * T + ni * 16 + r] = acc[mi][ni][j];
        }
        return;
    }
    // ---- GEMM path: xy = Ah*Bh^T, 1 MFMA term, register-direct ----
    int oo = o - SYRK_BLKS_PAD;  // 0..624; SYRK_BLKS_PAD%8==0 keeps oo%8==o%8
    int xcd = oo & 7, slot = oo >> 3;
    int v = (xcd < 1 ? xcd * 79 : 79 + (xcd - 1) * 78) + slot;  // bijective over 625=8*78+1
    int bm = v / 5, bn = v % 5;
    int wr = wid >> 1, wc = wid & 1;
    int m0 = bm * 128 + wr * 64, n0 = bn * 128 + wc * 64;  // this wave's 64x64 tile
    int q0 = m0 >> 5;   // two query samples (mi>>1 selects)
    int p0 = n0 >> 5;   // two protos (ni>>1 selects)
    const half8* pA0 = Ah + (size_t)q0 * SAMP_STRIDE + g * 32 + r;
    const half8* pA1 = pA0 + SAMP_STRIDE;
    const half8* pB = Bh + (size_t)g * NPROWS + n0 + r;
    f32x4 acc[4][4];
    f32x4 zero = {0.f, 0.f, 0.f, 0.f};
#pragma unroll
    for (int mi = 0; mi < 4; mi++)
#pragma unroll
        for (int ni = 0; ni < 4; ni++) acc[mi][ni] = zero;
#pragma unroll 2
    for (int t = 0; t < C / 32; t++) {
        half8 ah[4], bh[4];
        ah[0] = pA0[0];   // query q0, rows r     (mi 0,1)
        ah[1] = pA0[16];  // query q0, rows 16+r
        ah[2] = pA1[0];   // query q0+1           (mi 2,3)
        ah[3] = pA1[16];
#pragma unroll
        for (int i = 0; i < 4; i++) bh[i] = pB[i * 16];
        pA0 += 128;
        pA1 += 128;
        pB += 4 * NPROWS;
#pragma unroll
        for (int mi = 0; mi < 4; mi++)
#pragma unroll
            for (int ni = 0; ni < 4; ni++)
                acc[mi][ni] = __builtin_amdgcn_mfma_f32_16x16x32_f16(ah[mi], bh[ni], acc[mi][ni], 0, 0, 0);
    }
    // blocked C-write: row = m0+mi*16+g*4+j -> (q0+(mi>>1), rin=(mi&1)*16+g*4+j)
    //                  col = n0+ni*16+r    -> (p0+(ni>>1), cin=(ni&1)*16+r)
#pragma unroll
    for (int mi = 0; mi < 4; mi++)
#pragma unroll
        for (int ni = 0; ni < 4; ni++) {
            float* ob = xy + ((size_t)(q0 + (mi >> 1)) * NCLASS + p0 + (ni >> 1)) * 1024 +
                        ((mi & 1) * 16 + g * 4) * 32 + (ni & 1) * 16 + r;
#pragma unroll
            for (int j = 0; j < 4; j++)
                ob[j * 32] = acc[mi][ni][j];
        }
}

// ---------------- wavefront soft-DTW: all matrices 4KB-blocked, stride 32 ---------
// rterm_j = gxx[q][j][j], cterm_j = gyy[m][j][j] (diag reuse).
__global__ __launch_bounds__(256) void softdtw_wave_kernel(
        const float* __restrict__ xy, const float* __restrict__ gxx,
        const float* __restrict__ gyy, float* __restrict__ dxy,
        float* __restrict__ dxx, float* __restrict__ dyy) {
    int tid = threadIdx.x;
    int j = tid & 31;                       // column within the matrix
    int mm = blockIdx.x * 8 + (tid >> 5);   // 8 matrices per 256-thread block
    bool valid = mm < NMM;
    int mmc = valid ? mm : 0;
    const float* rbase;
    const float* cbase;
    const float* cptr;
    float* outp;
    if (mmc < NQ * NCLASS) {
        int q = mmc / NCLASS, m = mmc % NCLASS;
        rbase = gxx + (size_t)q * (T * T);
        cbase = gyy + (size_t)m * (T * T);
        cptr = xy + (size_t)mmc * (T * T);   // blocked: contiguous 4KB matrix
        outp = dxy + mmc;
    } else if (mmc < NQ * NCLASS + NQ) {
        int i = mmc - NQ * NCLASS;
        rbase = gxx + (size_t)i * (T * T);
        cbase = rbase;
        cptr = rbase;
        outp = dxx + i;
    } else {
        int i = mmc - NQ * NCLASS - NQ;
        rbase = gyy + (size_t)i * (T * T);
        cbase = rbase;
        cptr = rbase;
        outp = dyy + i;
    }
    float cjv = cbase[j * 33];  // diag element (j,j)
    float xreg = rbase[j * 33]; // lane l holds rterm[l]; shuffled per step
    float my_prev = BIG, my_prev2 = BIG;
    int ip = 0 - j; ip = ip < 0 ? 0 : (ip > 31 ? 31 : ip);
    float nxt_xy = cptr[ip * T + j];
    for (int k = 0; k < 63; k++) {
        float cur_xy = nxt_xy;
        int in = k + 1 - j; in = in < 0 ? 0 : (in > 31 ? 31 : in);
        nxt_xy = cptr[in * T + j];   // prefetch next anti-diagonal (stride 32 always)
        float lp = __shfl_up(my_prev, 1, 32);
        float dg = __shfl_up(my_prev2, 1, 32);
        if (j == 0) { lp = BIG; dg = (k == 0) ? 0.f : BIG; }
        float up = my_prev;
        int i = k - j;
        float ai = __shfl(xreg, i & 31, 32);
        float d = ai + cjv - 2.0f * cur_xy;
        float mn = fminf(dg, fminf(up, lp));
        float ssum = __expf((mn - dg) * INVG) + __expf((mn - up) * INVG) +
                     __expf((mn - lp) * INVG);
        float r = d + mn - GAMMA * __logf(ssum);
        bool active = (i >= 0) && (i < 32);
        my_prev2 = my_prev;
        my_prev = active ? r : my_prev;
    }
    if (j == 31 && valid) *outp = my_prev;  // R[31][31]
}

// ---------------- finalize: dist, log-softmax, loss, acc ----------------
__global__ __launch_bounds__(512) void finalize_kernel(const float* __restrict__ dxy,
                                                       const float* __restrict__ dxx,
                                                       const float* __restrict__ dyy,
                                                       float* __restrict__ out) {
    __shared__ float sl[512];
    __shared__ float sa[512];
    int q = threadIdx.x;
    float bl = 0.f, fl = 0.f;
    if (q < NQ) {
        float dxxq = dxx[q];
        int cq = q / NQPC;
        float dd[NCLASS];
#pragma unroll
        for (int m = 0; m < NCLASS; m++)
            dd[m] = dxy[q * NCLASS + m] - 0.5f * (dxxq + dyy[m]);
        float best = dd[0];
        int bi = 0;
#pragma unroll
        for (int m = 1; m < NCLASS; m++) {
            if (dd[m] < best) { best = dd[m]; bi = m; }
        }
        float s = 0.f;
        float dcq = dd[0];
#pragma unroll
        for (int m = 0; m < NCLASS; m++) {
            s += __expf(best - dd[m]);
            if (m == cq) dcq = dd[m];
        }
        float lse = __logf(s) - best;
        bl = dcq + lse;
        out[2 + q] = bl;
        fl = (bi == cq) ? 1.f : 0.f;
    }
    sl[threadIdx.x] = bl;
    sa[threadIdx.x] = fl;
    __syncthreads();
    for (int off = 256; off; off >>= 1) {
        if (threadIdx.x < off) {
            sl[threadIdx.x] += sl[threadIdx.x + off];
            sa[threadIdx.x] += sa[threadIdx.x + off];
        }
        __syncthreads();
    }
    if (threadIdx.x == 0) {
        out[0] = sl[0] / (float)NQ;
        out[1] = sa[0] / (float)NQ;
    }
}

extern "C" void kernel_launch(void* const* d_in, const int* in_sizes, int n_in,
                              void* d_out, int out_size, void* d_ws, size_t ws_size,
                              hipStream_t stream) {
    const float* inp = (const float*)d_in[0];
    const int* target = (const int*)d_in[1];
    float* out = (float*)d_out;
    char* ws = (char*)d_ws;

    size_t off = 0;
    auto carve = [&](size_t bytes) {
        void* p = ws + off;
        off = (off + bytes + 255) & ~(size_t)255;
        return p;
    };
    int* order = (int*)carve(NTOT * sizeof(int));
    int* qsrc = (int*)carve(NQ * sizeof(int));
    float* xy = (float*)carve((size_t)NQ * NCLASS * T * T * sizeof(float));  // 41 MB blocked
    float* gxx = (float*)carve((size_t)NQ * T * T * sizeof(float));
    float* gyy = (float*)carve((size_t)NCLASS * T * T * sizeof(float));
    float* dxy = (float*)carve((size_t)NQ * NCLASS * sizeof(float));
    float* dxx = (float*)carve((size_t)NQ * sizeof(float));
    float* dyy = (float*)carve((size_t)NCLASS * sizeof(float));
    half8* Ah = (half8*)carve((size_t)NQ * SAMP_STRIDE * 16);  // 65.5 MB per-query
    half8* Bh = (half8*)carve((size_t)(C / 8) * NPROWS * 16);  // 2.6 MB (L2-resident)
    (void)ws_size;

    sort_kernel<<<1, 640, 0, stream>>>(target, order, qsrc);
    stage_kernel<<<STAGE_BLKS_A + STAGE_BLKS_B, 256, 0, stream>>>(inp, qsrc, order, Ah, Bh);
    gemm_syrk_kernel<<<SYRK_BLKS_PAD + GEMM_BLKS, 256, 0, stream>>>(Ah, Bh, xy, gxx, gyy);
    softdtw_wave_kernel<<<(NMM + 7) / 8, 256, 0, stream>>>(xy, gxx, gyy, dxy, dxx, dyy);
    finalize_kernel<<<1, 512, 0, stream>>>(dxy, dxx, dyy, out);
}

// Round 21
// 164.189 us; speedup vs baseline: 1.2754x; 1.0475x over previous
//
#include <hip/hip_runtime.h>

#define T 32
#define C 2048
#define NTOT 600
#define NCLASS 20
#define NSUP 5
#define PER 30
#define NQPC 25
#define NQ 500
#define NQROWS (NQ * T)      // 16000
#define NPROWS (NCLASS * T)  // 640
#define GAMMA 0.1f
#define INVG 10.0f
#define BIG 1e10f
#define NSELF (NQ + NCLASS)  // 520
#define GEMM_BLKS 625
#define SYRK_BLKS_PAD 136  // multiple of 8 so gemm swizzle sees o%8 unchanged
#define SAMP_STRIDE 8192   // half8 per staged query sample: 256 chunks x 32 rows
#define STAGE_BLKS_A 2000  // (500*32/16 row-tiles) x 2 col-halves
#define STAGE_BLKS_B 80    // (640/16) x 2
#define LDS_PITCH 33       // half8 per LDS row (32 chunks + 1 pad)

typedef __fp16 half8 __attribute__((ext_vector_type(8)));
typedef __fp16 half4 __attribute__((ext_vector_type(4)));
typedef float f32x4 __attribute__((ext_vector_type(4)));

// ---------------- parallel stable counting sort (1 block) ----------------
__global__ __launch_bounds__(640) void sort_kernel(const int* __restrict__ target,
                                                   int* __restrict__ order,
                                                   int* __restrict__ qsrc) {
    __shared__ int tgt[NTOT];
    __shared__ int offs[NCLASS];
    __shared__ int ordl[NTOT];
    int tid = threadIdx.x;
    if (tid < NTOT) tgt[tid] = target[tid];
    __syncthreads();
    if (tid < NCLASS) {
        int o = 0;
        for (int i = 0; i < NTOT; i++) o += (tgt[i] < tid) ? 1 : 0;
        offs[tid] = o;
    }
    __syncthreads();
    if (tid < NTOT) {
        int c = tgt[tid];
        int rank = 0;
        for (int k = 0; k < NTOT; k++) rank += (k < tid && tgt[k] == c) ? 1 : 0;
        ordl[offs[c] + rank] = tid;
    }
    __syncthreads();
    if (tid < NTOT) order[tid] = ordl[tid];
    if (tid < NQ) qsrc[tid] = ordl[(tid / NQPC) * PER + NSUP + (tid % NQPC)];
}

// ---------------- staging: gather + f16 round + LDS transpose + norm partials -----
// Also emits per-(row, wave, half) partial sums of ROUNDED squares:
// x2part[row*8 + half*4 + w], y2part likewise (deterministic, no atomics).
__global__ __launch_bounds__(256) void stage_kernel(const float* __restrict__ inp,
                                                    const int* __restrict__ qsrc,
                                                    const int* __restrict__ order,
                                                    half8* __restrict__ Ah,
                                                    half8* __restrict__ Bh,
                                                    float* __restrict__ x2part,
                                                    float* __restrict__ y2part) {
    __shared__ half8 lds[4][16][LDS_PITCH];  // 33.8 KB
    int tid = threadIdx.x;
    int lane = tid & 63, w = tid >> 6;
    int bid = blockIdx.x;
    bool isA = bid < STAGE_BLKS_A;
    int b = isA ? bid : bid - STAGE_BLKS_A;
    int rowblk = b >> 1, half = b & 1;
    int row0 = rowblk * 16;
    int colbase = half * 1024 + w * 256;  // this wave's float-col window
    int pidx = half * 4 + w;              // partial slot 0..7
    if (isA) {
        int q = row0 >> 5, rowin0 = row0 & 31;  // 16-row tile within one query sample
        const float* sbase = inp + (size_t)qsrc[q] * (T * C) + (size_t)rowin0 * C +
                             colbase + lane * 4;
#pragma unroll
        for (int rr = 0; rr < 16; rr++) {
            float4 v = *(const float4*)(sbase + (size_t)rr * C);
            half4 hv = {(__fp16)v.x, (__fp16)v.y, (__fp16)v.z, (__fp16)v.w};
            ((half4*)&lds[w][rr][0])[lane] = hv;  // contiguous 512B per wave
            float fx = (float)hv[0], fy = (float)hv[1], fz = (float)hv[2], fw = (float)hv[3];
            float s = fx * fx + fy * fy + fz * fz + fw * fw;
#pragma unroll
            for (int d = 1; d < 64; d <<= 1) s += __shfl_xor(s, d);
            if (lane == 0) x2part[(size_t)(row0 + rr) * 8 + pidx] = s;
        }
        __syncthreads();
        int chunkbase = half * 128 + w * 32;
        half8* dst = Ah + (size_t)q * SAMP_STRIDE + rowin0;
#pragma unroll
        for (int c = 0; c < 8; c++) {
            int idx = c * 64 + lane;         // 0..511
            int ch = idx >> 4, row = idx & 15;
            dst[(size_t)(chunkbase + ch) * 32 + row] = lds[w][row][ch];
        }
    } else {
#pragma unroll
        for (int rr = 0; rr < 16; rr++) {
            int rg = row0 + rr;
            int cls = rg >> 5, trow = rg & 31;
            const float* base = inp + (size_t)trow * C + colbase + lane * 4;
            float4 a = *(const float4*)(base + (size_t)order[cls * PER + 0] * (T * C));
            float4 b4 = *(const float4*)(base + (size_t)order[cls * PER + 1] * (T * C));
            float4 c = *(const float4*)(base + (size_t)order[cls * PER + 2] * (T * C));
            float4 d = *(const float4*)(base + (size_t)order[cls * PER + 3] * (T * C));
            float4 e = *(const float4*)(base + (size_t)order[cls * PER + 4] * (T * C));
            float4 m;
            m.x = (a.x + b4.x + c.x + d.x + e.x) * 0.2f;
            m.y = (a.y + b4.y + c.y + d.y + e.y) * 0.2f;
            m.z = (a.z + b4.z + c.z + d.z + e.z) * 0.2f;
            m.w = (a.w + b4.w + c.w + d.w + e.w) * 0.2f;
            half4 hv = {(__fp16)m.x, (__fp16)m.y, (__fp16)m.z, (__fp16)m.w};
            ((half4*)&lds[w][rr][0])[lane] = hv;
            float fx = (float)hv[0], fy = (float)hv[1], fz = (float)hv[2], fw = (float)hv[3];
            float s = fx * fx + fy * fy + fz * fz + fw * fw;
#pragma unroll
            for (int dd = 1; dd < 64; dd <<= 1) s += __shfl_xor(s, dd);
            if (lane == 0) y2part[(size_t)rg * 8 + pidx] = s;
        }
        __syncthreads();
        int chunkbase = half * 128 + w * 32;
#pragma unroll
        for (int c = 0; c < 8; c++) {
            int idx = c * 64 + lane;
            int ch = idx >> 4, row = idx & 15;
            Bh[(size_t)(chunkbase + ch) * NPROWS + row0 + row] = lds[w][row][ch];
        }
    }
}

// ---------------- merged: SYRK + GEMM with FUSED cross soft-DTW epilogue ----------
// GEMM main loop unchanged (register-direct, no barriers). Epilogue: each wave's
// acc = 4 complete 32x32 cost-dot matrices; scatter 2/pass to wave-private LDS and
// run the 32-lane wavefront DTW in place. Only dxy (4 floats/wave) hits memory.
__global__ __launch_bounds__(256) void gemm_syrk_kernel(const half8* __restrict__ Ah,
                                                        const half8* __restrict__ Bh,
                                                        const float* __restrict__ x2part,
                                                        const float* __restrict__ y2part,
                                                        float* __restrict__ dxy,
                                                        float* __restrict__ gxx,
                                                        float* __restrict__ gyy) {
    __shared__ float dmat[4][2][32][32];  // per-wave 2-matrix DTW tile, 32 KB
    int tid = threadIdx.x, lane = tid & 63, wid = tid >> 6;
    int o = blockIdx.x;
    int g = lane >> 4, r = lane & 15;
    if (o < SYRK_BLKS_PAD) {
        // ---- SYRK path: one wave per 32x32 Gram matrix (short blocks first) ----
        int ww = o * 4 + wid;
        if (ww >= NSELF) return;
        f32x4 acc[2][2];
        f32x4 zero = {0.f, 0.f, 0.f, 0.f};
        acc[0][0] = zero; acc[0][1] = zero; acc[1][0] = zero; acc[1][1] = zero;
        if (ww < NQ) {
            const half8* p = Ah + (size_t)ww * SAMP_STRIDE + g * 32 + r;
            float* outp = gxx + (size_t)ww * (T * T);
            for (int t = 0; t < C / 32; t++) {
                half8 h0 = p[0], h1 = p[16];
                p += 128;  // next 4 chunks
                acc[0][0] = __builtin_amdgcn_mfma_f32_16x16x32_f16(h0, h0, acc[0][0], 0, 0, 0);
                acc[0][1] = __builtin_amdgcn_mfma_f32_16x16x32_f16(h0, h1, acc[0][1], 0, 0, 0);
                acc[1][0] = __builtin_amdgcn_mfma_f32_16x16x32_f16(h1, h0, acc[1][0], 0, 0, 0);
                acc[1][1] = __builtin_amdgcn_mfma_f32_16x16x32_f16(h1, h1, acc[1][1], 0, 0, 0);
            }
#pragma unroll
            for (int mi = 0; mi < 2; mi++)
#pragma unroll
                for (int ni = 0; ni < 2; ni++)
#pragma unroll
                    for (int j = 0; j < 4; j++)
                        outp[(mi * 16 + g * 4 + j) * T + ni * 16 + r] = acc[mi][ni][j];
        } else {
            int row0 = (ww - NQ) * 32;
            float* outp = gyy + (size_t)(ww - NQ) * (T * T);
            for (int t = 0; t < C / 32; t++) {
                size_t base = (size_t)(t * 4 + g) * NPROWS + row0 + r;
                half8 h0 = Bh[base], h1 = Bh[base + 16];
                acc[0][0] = __builtin_amdgcn_mfma_f32_16x16x32_f16(h0, h0, acc[0][0], 0, 0, 0);
                acc[0][1] = __builtin_amdgcn_mfma_f32_16x16x32_f16(h0, h1, acc[0][1], 0, 0, 0);
                acc[1][0] = __builtin_amdgcn_mfma_f32_16x16x32_f16(h1, h0, acc[1][0], 0, 0, 0);
                acc[1][1] = __builtin_amdgcn_mfma_f32_16x16x32_f16(h1, h1, acc[1][1], 0, 0, 0);
            }
#pragma unroll
            for (int mi = 0; mi < 2; mi++)
#pragma unroll
                for (int ni = 0; ni < 2; ni++)
#pragma unroll
                    for (int j = 0; j < 4; j++)
                        outp[(mi * 16 + g * 4 + j) * T + ni * 16 + r] = acc[mi][ni][j];
        }
        return;
    }
    // ---- GEMM path: dots = Ah*Bh^T, 1 MFMA term, register-direct ----
    int oo = o - SYRK_BLKS_PAD;  // 0..624; SYRK_BLKS_PAD%8==0 keeps oo%8==o%8
    int xcd = oo & 7, slot = oo >> 3;
    int v = (xcd < 1 ? xcd * 79 : 79 + (xcd - 1) * 78) + slot;  // bijective over 625=8*78+1
    int bm = v / 5, bn = v % 5;
    int wr = wid >> 1, wc = wid & 1;
    int m0 = bm * 128 + wr * 64, n0 = bn * 128 + wc * 64;  // this wave's 64x64 tile
    int q0 = m0 >> 5;   // two query samples
    int p0 = n0 >> 5;   // two protos
    const half8* pA0 = Ah + (size_t)q0 * SAMP_STRIDE + g * 32 + r;
    const half8* pA1 = pA0 + SAMP_STRIDE;
    const half8* pB = Bh + (size_t)g * NPROWS + n0 + r;
    f32x4 acc[4][4];
    f32x4 zero = {0.f, 0.f, 0.f, 0.f};
#pragma unroll
    for (int mi = 0; mi < 4; mi++)
#pragma unroll
        for (int ni = 0; ni < 4; ni++) acc[mi][ni] = zero;
#pragma unroll 2
    for (int t = 0; t < C / 32; t++) {
        half8 ah[4], bh[4];
        ah[0] = pA0[0];
        ah[1] = pA0[16];
        ah[2] = pA1[0];
        ah[3] = pA1[16];
#pragma unroll
        for (int i = 0; i < 4; i++) bh[i] = pB[i * 16];
        pA0 += 128;
        pA1 += 128;
        pB += 4 * NPROWS;
#pragma unroll
        for (int mi = 0; mi < 4; mi++)
#pragma unroll
            for (int ni = 0; ni < 4; ni++)
                acc[mi][ni] = __builtin_amdgcn_mfma_f32_16x16x32_f16(ah[mi], bh[ni], acc[mi][ni], 0, 0, 0);
    }
    // ---- fused cross soft-DTW epilogue ----
    int jj = lane & 31;
    int hh = lane >> 5;  // which query of the pair this 32-lane half handles
    float xreg = 0.f;    // x2 of row jj of query q0+hh (sum of 8 staged partials)
    {
        const float* xp = x2part + ((size_t)(q0 + hh) * 32 + jj) * 8;
#pragma unroll
        for (int p = 0; p < 8; p++) xreg += xp[p];
    }
#pragma unroll
    for (int pp = 0; pp < 2; pp++) {
        __syncthreads();  // protect prior pass reads before overwriting dmat
#pragma unroll
        for (int qi = 0; qi < 2; qi++)
#pragma unroll
            for (int m2 = 0; m2 < 2; m2++)
#pragma unroll
                for (int nn = 0; nn < 2; nn++)
#pragma unroll
                    for (int j = 0; j < 4; j++)
                        dmat[wid][qi][m2 * 16 + g * 4 + j][nn * 16 + r] =
                            acc[qi * 2 + m2][pp * 2 + nn][j];
        __syncthreads();
        float cjv = 0.f;  // y2 of proto row jj of proto p0+pp
        {
            const float* yp = y2part + ((size_t)(p0 + pp) * 32 + jj) * 8;
#pragma unroll
            for (int p = 0; p < 8; p++) cjv += yp[p];
        }
        const float* cm = &dmat[wid][hh][0][0];
        float my_prev = BIG, my_prev2 = BIG;
        int ip = 0 - jj; ip = ip < 0 ? 0 : ip;
        float nxt = cm[ip * 32 + jj];
        for (int k = 0; k < 63; k++) {
            float cur = nxt;
            int in = k + 1 - jj; in = in < 0 ? 0 : (in > 31 ? 31 : in);
            nxt = cm[in * 32 + jj];  // bank = jj: conflict-free
            float lp = __shfl_up(my_prev, 1, 32);
            float dg = __shfl_up(my_prev2, 1, 32);
            if (jj == 0) { lp = BIG; dg = (k == 0) ? 0.f : BIG; }
            float up = my_prev;
            int i = k - jj;
            float ai = __shfl(xreg, i & 31, 32);
            float d = ai + cjv - 2.0f * cur;
            float mn = fminf(dg, fminf(up, lp));
            float ssum = __expf((mn - dg) * INVG) + __expf((mn - up) * INVG) +
                         __expf((mn - lp) * INVG);
            float rv = d + mn - GAMMA * __logf(ssum);
            bool act = (i >= 0) && (i < 32);
            my_prev2 = my_prev;
            my_prev = act ? rv : my_prev;
        }
        if (jj == 31) dxy[(size_t)(q0 + hh) * NCLASS + p0 + pp] = my_prev;
    }
}

// ---------------- wavefront soft-DTW for the 520 self matrices --------------------
// rterm = cterm = diag(G); cost matrix = G itself (4KB blocked, stride 32).
__global__ __launch_bounds__(256) void softdtw_self_kernel(
        const float* __restrict__ gxx, const float* __restrict__ gyy,
        float* __restrict__ dxx, float* __restrict__ dyy) {
    int tid = threadIdx.x;
    int jj = tid & 31;
    int mm = blockIdx.x * 8 + (tid >> 5);
    bool valid = mm < NSELF;
    int mmc = valid ? mm : 0;
    const float* base = (mmc < NQ) ? gxx + (size_t)mmc * (T * T)
                                   : gyy + (size_t)(mmc - NQ) * (T * T);
    float* outp = (mmc < NQ) ? dxx + mmc : dyy + (mmc - NQ);
    float cjv = base[jj * 33];  // diag (j,j)
    float xreg = cjv;
    float my_prev = BIG, my_prev2 = BIG;
    int ip = 0 - jj; ip = ip < 0 ? 0 : ip;
    float nxt = base[ip * T + jj];
    for (int k = 0; k < 63; k++) {
        float cur = nxt;
        int in = k + 1 - jj; in = in < 0 ? 0 : (in > 31 ? 31 : in);
        nxt = base[in * T + jj];
        float lp = __shfl_up(my_prev, 1, 32);
        float dg = __shfl_up(my_prev2, 1, 32);
        if (jj == 0) { lp = BIG; dg = (k == 0) ? 0.f : BIG; }
        float up = my_prev;
        int i = k - jj;
        float ai = __shfl(xreg, i & 31, 32);
        float d = ai + cjv - 2.0f * cur;
        float mn = fminf(dg, fminf(up, lp));
        float ssum = __expf((mn - dg) * INVG) + __expf((mn - up) * INVG) +
                     __expf((mn - lp) * INVG);
        float rv = d + mn - GAMMA * __logf(ssum);
        bool act = (i >= 0) && (i < 32);
        my_prev2 = my_prev;
        my_prev = act ? rv : my_prev;
    }
    if (jj == 31 && valid) *outp = my_prev;
}

// ---------------- finalize: dist, log-softmax, loss, acc ----------------
__global__ __launch_bounds__(512) void finalize_kernel(const float* __restrict__ dxy,
                                                       const float* __restrict__ dxx,
                                                       const float* __restrict__ dyy,
                                                       float* __restrict__ out) {
    __shared__ float sl[512];
    __shared__ float sa[512];
    int q = threadIdx.x;
    float bl = 0.f, fl = 0.f;
    if (q < NQ) {
        float dxxq = dxx[q];
        int cq = q / NQPC;
        float dd[NCLASS];
#pragma unroll
        for (int m = 0; m < NCLASS; m++)
            dd[m] = dxy[q * NCLASS + m] - 0.5f * (dxxq + dyy[m]);
        float best = dd[0];
        int bi = 0;
#pragma unroll
        for (int m = 1; m < NCLASS; m++) {
            if (dd[m] < best) { best = dd[m]; bi = m; }
        }
        float s = 0.f;
        float dcq = dd[0];
#pragma unroll
        for (int m = 0; m < NCLASS; m++) {
            s += __expf(best - dd[m]);
            if (m == cq) dcq = dd[m];
        }
        float lse = __logf(s) - best;
        bl = dcq + lse;
        out[2 + q] = bl;
        fl = (bi == cq) ? 1.f : 0.f;
    }
    sl[threadIdx.x] = bl;
    sa[threadIdx.x] = fl;
    __syncthreads();
    for (int off = 256; off; off >>= 1) {
        if (threadIdx.x < off) {
            sl[threadIdx.x] += sl[threadIdx.x + off];
            sa[threadIdx.x] += sa[threadIdx.x + off];
        }
        __syncthreads();
    }
    if (threadIdx.x == 0) {
        out[0] = sl[0] / (float)NQ;
        out[1] = sa[0] / (float)NQ;
    }
}

extern "C" void kernel_launch(void* const* d_in, const int* in_sizes, int n_in,
                              void* d_out, int out_size, void* d_ws, size_t ws_size,
                              hipStream_t stream) {
    const float* inp = (const float*)d_in[0];
    const int* target = (const int*)d_in[1];
    float* out = (float*)d_out;
    char* ws = (char*)d_ws;

    size_t off = 0;
    auto carve = [&](size_t bytes) {
        void* p = ws + off;
        off = (off + bytes + 255) & ~(size_t)255;
        return p;
    };
    int* order = (int*)carve(NTOT * sizeof(int));
    int* qsrc = (int*)carve(NQ * sizeof(int));
    float* x2part = (float*)carve((size_t)NQROWS * 8 * sizeof(float));  // 512 KB
    float* y2part = (float*)carve((size_t)NPROWS * 8 * sizeof(float));  // 20 KB
    float* gxx = (float*)carve((size_t)NQ * T * T * sizeof(float));
    float* gyy = (float*)carve((size_t)NCLASS * T * T * sizeof(float));
    float* dxy = (float*)carve((size_t)NQ * NCLASS * sizeof(float));
    float* dxx = (float*)carve((size_t)NQ * sizeof(float));
    float* dyy = (float*)carve((size_t)NCLASS * sizeof(float));
    half8* Ah = (half8*)carve((size_t)NQ * SAMP_STRIDE * 16);  // 65.5 MB per-query
    half8* Bh = (half8*)carve((size_t)(C / 8) * NPROWS * 16);  // 2.6 MB (L2-resident)
    (void)ws_size;

    sort_kernel<<<1, 640, 0, stream>>>(target, order, qsrc);
    stage_kernel<<<STAGE_BLKS_A + STAGE_BLKS_B, 256, 0, stream>>>(inp, qsrc, order, Ah, Bh,
                                                                  x2part, y2part);
    gemm_syrk_kernel<<<SYRK_BLKS_PAD + GEMM_BLKS, 256, 0, stream>>>(Ah, Bh, x2part, y2part,
                                                                    dxy, gxx, gyy);
    softdtw_self_kernel<<<(NSELF + 7) / 8, 256, 0, stream>>>(gxx, gyy, dxx, dyy);
    finalize_kernel<<<1, 512, 0, stream>>>(dxy, dxx, dyy, out);
}

// Round 22
// 162.014 us; speedup vs baseline: 1.2925x; 1.0134x over previous
//
#include <hip/hip_runtime.h>

#define T 32
#define C 2048
#define NTOT 600
#define NCLASS 20
#define NSUP 5
#define PER 30
#define NQPC 25
#define NQ 500
#define NQROWS (NQ * T)      // 16000
#define NPROWS (NCLASS * T)  // 640
#define GAMMA 0.1f
#define INVG 10.0f
#define BIG 1e10f
#define NSELF (NQ + NCLASS)  // 520
#define GEMM_BLKS 625
#define SYRK_BLKS_PAD 136  // multiple of 8 so gemm swizzle sees o%8 unchanged
#define SAMP_STRIDE 8192   // half8 per staged query sample: 256 chunks x 32 rows
#define STAGE_BLKS_A 2000  // (500*32/16 row-tiles) x 2 col-halves
#define STAGE_BLKS_B 80    // (640/16) x 2
#define LDS_PITCH 33       // half8 per LDS row (32 chunks + 1 pad)

typedef __fp16 half8 __attribute__((ext_vector_type(8)));
typedef __fp16 half4 __attribute__((ext_vector_type(4)));
typedef float f32x4 __attribute__((ext_vector_type(4)));

// ---------------- parallel stable counting sort (1 block) ----------------
__global__ __launch_bounds__(640) void sort_kernel(const int* __restrict__ target,
                                                   int* __restrict__ order,
                                                   int* __restrict__ qsrc) {
    __shared__ int tgt[NTOT];
    __shared__ int offs[NCLASS];
    __shared__ int ordl[NTOT];
    int tid = threadIdx.x;
    if (tid < NTOT) tgt[tid] = target[tid];
    __syncthreads();
    if (tid < NCLASS) {
        int o = 0;
        for (int i = 0; i < NTOT; i++) o += (tgt[i] < tid) ? 1 : 0;
        offs[tid] = o;
    }
    __syncthreads();
    if (tid < NTOT) {
        int c = tgt[tid];
        int rank = 0;
        for (int k = 0; k < NTOT; k++) rank += (k < tid && tgt[k] == c) ? 1 : 0;
        ordl[offs[c] + rank] = tid;
    }
    __syncthreads();
    if (tid < NTOT) order[tid] = ordl[tid];
    if (tid < NQ) qsrc[tid] = ordl[(tid / NQPC) * PER + NSUP + (tid % NQPC)];
}

// ---------------- staging: gather + f16 round + LDS transpose + norm partials -----
__global__ __launch_bounds__(256) void stage_kernel(const float* __restrict__ inp,
                                                    const int* __restrict__ qsrc,
                                                    const int* __restrict__ order,
                                                    half8* __restrict__ Ah,
                                                    half8* __restrict__ Bh,
                                                    float* __restrict__ x2part,
                                                    float* __restrict__ y2part) {
    __shared__ half8 lds[4][16][LDS_PITCH];  // 33.8 KB
    int tid = threadIdx.x;
    int lane = tid & 63, w = tid >> 6;
    int bid = blockIdx.x;
    bool isA = bid < STAGE_BLKS_A;
    int b = isA ? bid : bid - STAGE_BLKS_A;
    int rowblk = b >> 1, half = b & 1;
    int row0 = rowblk * 16;
    int colbase = half * 1024 + w * 256;  // this wave's float-col window
    int pidx = half * 4 + w;              // partial slot 0..7
    if (isA) {
        int q = row0 >> 5, rowin0 = row0 & 31;  // 16-row tile within one query sample
        const float* sbase = inp + (size_t)qsrc[q] * (T * C) + (size_t)rowin0 * C +
                             colbase + lane * 4;
#pragma unroll
        for (int rr = 0; rr < 16; rr++) {
            float4 v = *(const float4*)(sbase + (size_t)rr * C);
            half4 hv = {(__fp16)v.x, (__fp16)v.y, (__fp16)v.z, (__fp16)v.w};
            ((half4*)&lds[w][rr][0])[lane] = hv;  // contiguous 512B per wave
            float fx = (float)hv[0], fy = (float)hv[1], fz = (float)hv[2], fw = (float)hv[3];
            float s = fx * fx + fy * fy + fz * fz + fw * fw;
#pragma unroll
            for (int d = 1; d < 64; d <<= 1) s += __shfl_xor(s, d);
            if (lane == 0) x2part[(size_t)(row0 + rr) * 8 + pidx] = s;
        }
        __syncthreads();
        int chunkbase = half * 128 + w * 32;
        half8* dst = Ah + (size_t)q * SAMP_STRIDE + rowin0;
#pragma unroll
        for (int c = 0; c < 8; c++) {
            int idx = c * 64 + lane;         // 0..511
            int ch = idx >> 4, row = idx & 15;
            dst[(size_t)(chunkbase + ch) * 32 + row] = lds[w][row][ch];
        }
    } else {
#pragma unroll
        for (int rr = 0; rr < 16; rr++) {
            int rg = row0 + rr;
            int cls = rg >> 5, trow = rg & 31;
            const float* base = inp + (size_t)trow * C + colbase + lane * 4;
            float4 a = *(const float4*)(base + (size_t)order[cls * PER + 0] * (T * C));
            float4 b4 = *(const float4*)(base + (size_t)order[cls * PER + 1] * (T * C));
            float4 c = *(const float4*)(base + (size_t)order[cls * PER + 2] * (T * C));
            float4 d = *(const float4*)(base + (size_t)order[cls * PER + 3] * (T * C));
            float4 e = *(const float4*)(base + (size_t)order[cls * PER + 4] * (T * C));
            float4 m;
            m.x = (a.x + b4.x + c.x + d.x + e.x) * 0.2f;
            m.y = (a.y + b4.y + c.y + d.y + e.y) * 0.2f;
            m.z = (a.z + b4.z + c.z + d.z + e.z) * 0.2f;
            m.w = (a.w + b4.w + c.w + d.w + e.w) * 0.2f;
            half4 hv = {(__fp16)m.x, (__fp16)m.y, (__fp16)m.z, (__fp16)m.w};
            ((half4*)&lds[w][rr][0])[lane] = hv;
            float fx = (float)hv[0], fy = (float)hv[1], fz = (float)hv[2], fw = (float)hv[3];
            float s = fx * fx + fy * fy + fz * fz + fw * fw;
#pragma unroll
            for (int dd = 1; dd < 64; dd <<= 1) s += __shfl_xor(s, dd);
            if (lane == 0) y2part[(size_t)rg * 8 + pidx] = s;
        }
        __syncthreads();
        int chunkbase = half * 128 + w * 32;
#pragma unroll
        for (int c = 0; c < 8; c++) {
            int idx = c * 64 + lane;
            int ch = idx >> 4, row = idx & 15;
            Bh[(size_t)(chunkbase + ch) * NPROWS + row0 + row] = lds[w][row][ch];
        }
    }
}

// ---------------- merged: SYRK + GEMM with FUSED cross soft-DTW epilogue ----------
// Epilogue DTW runs in INVG-SCALED domain: R' = R*INVG, so the per-step chain is
// min3 -> sub -> exp -> add -> log -> add (no mul by INVG / GAMMA on the chain).
__global__ __launch_bounds__(256) void gemm_syrk_kernel(const half8* __restrict__ Ah,
                                                        const half8* __restrict__ Bh,
                                                        const float* __restrict__ x2part,
                                                        const float* __restrict__ y2part,
                                                        float* __restrict__ dxy,
                                                        float* __restrict__ gxx,
                                                        float* __restrict__ gyy) {
    __shared__ float dmat[4][2][32][32];  // per-wave 2-matrix DTW tile, 32 KB
    int tid = threadIdx.x, lane = tid & 63, wid = tid >> 6;
    int o = blockIdx.x;
    int g = lane >> 4, r = lane & 15;
    if (o < SYRK_BLKS_PAD) {
        // ---- SYRK path: one wave per 32x32 Gram matrix (short blocks first) ----
        int ww = o * 4 + wid;
        if (ww >= NSELF) return;
        f32x4 acc[2][2];
        f32x4 zero = {0.f, 0.f, 0.f, 0.f};
        acc[0][0] = zero; acc[0][1] = zero; acc[1][0] = zero; acc[1][1] = zero;
        if (ww < NQ) {
            const half8* p = Ah + (size_t)ww * SAMP_STRIDE + g * 32 + r;
            float* outp = gxx + (size_t)ww * (T * T);
            for (int t = 0; t < C / 32; t++) {
                half8 h0 = p[0], h1 = p[16];
                p += 128;  // next 4 chunks
                acc[0][0] = __builtin_amdgcn_mfma_f32_16x16x32_f16(h0, h0, acc[0][0], 0, 0, 0);
                acc[0][1] = __builtin_amdgcn_mfma_f32_16x16x32_f16(h0, h1, acc[0][1], 0, 0, 0);
                acc[1][0] = __builtin_amdgcn_mfma_f32_16x16x32_f16(h1, h0, acc[1][0], 0, 0, 0);
                acc[1][1] = __builtin_amdgcn_mfma_f32_16x16x32_f16(h1, h1, acc[1][1], 0, 0, 0);
            }
#pragma unroll
            for (int mi = 0; mi < 2; mi++)
#pragma unroll
                for (int ni = 0; ni < 2; ni++)
#pragma unroll
                    for (int j = 0; j < 4; j++)
                        outp[(mi * 16 + g * 4 + j) * T + ni * 16 + r] = acc[mi][ni][j];
        } else {
            int row0 = (ww - NQ) * 32;
            float* outp = gyy + (size_t)(ww - NQ) * (T * T);
            for (int t = 0; t < C / 32; t++) {
                size_t base = (size_t)(t * 4 + g) * NPROWS + row0 + r;
                half8 h0 = Bh[base], h1 = Bh[base + 16];
                acc[0][0] = __builtin_amdgcn_mfma_f32_16x16x32_f16(h0, h0, acc[0][0], 0, 0, 0);
                acc[0][1] = __builtin_amdgcn_mfma_f32_16x16x32_f16(h0, h1, acc[0][1], 0, 0, 0);
                acc[1][0] = __builtin_amdgcn_mfma_f32_16x16x32_f16(h1, h0, acc[1][0], 0, 0, 0);
                acc[1][1] = __builtin_amdgcn_mfma_f32_16x16x32_f16(h1, h1, acc[1][1], 0, 0, 0);
            }
#pragma unroll
            for (int mi = 0; mi < 2; mi++)
#pragma unroll
                for (int ni = 0; ni < 2; ni++)
#pragma unroll
                    for (int j = 0; j < 4; j++)
                        outp[(mi * 16 + g * 4 + j) * T + ni * 16 + r] = acc[mi][ni][j];
        }
        return;
    }
    // ---- GEMM path: dots = Ah*Bh^T, 1 MFMA term, register-direct ----
    int oo = o - SYRK_BLKS_PAD;  // 0..624; SYRK_BLKS_PAD%8==0 keeps oo%8==o%8
    int xcd = oo & 7, slot = oo >> 3;
    int v = (xcd < 1 ? xcd * 79 : 79 + (xcd - 1) * 78) + slot;  // bijective over 625=8*78+1
    int bm = v / 5, bn = v % 5;
    int wr = wid >> 1, wc = wid & 1;
    int m0 = bm * 128 + wr * 64, n0 = bn * 128 + wc * 64;  // this wave's 64x64 tile
    int q0 = m0 >> 5;   // two query samples
    int p0 = n0 >> 5;   // two protos
    const half8* pA0 = Ah + (size_t)q0 * SAMP_STRIDE + g * 32 + r;
    const half8* pA1 = pA0 + SAMP_STRIDE;
    const half8* pB = Bh + (size_t)g * NPROWS + n0 + r;
    f32x4 acc[4][4];
    f32x4 zero = {0.f, 0.f, 0.f, 0.f};
#pragma unroll
    for (int mi = 0; mi < 4; mi++)
#pragma unroll
        for (int ni = 0; ni < 4; ni++) acc[mi][ni] = zero;
#pragma unroll 2
    for (int t = 0; t < C / 32; t++) {
        half8 ah[4], bh[4];
        ah[0] = pA0[0];
        ah[1] = pA0[16];
        ah[2] = pA1[0];
        ah[3] = pA1[16];
#pragma unroll
        for (int i = 0; i < 4; i++) bh[i] = pB[i * 16];
        pA0 += 128;
        pA1 += 128;
        pB += 4 * NPROWS;
#pragma unroll
        for (int mi = 0; mi < 4; mi++)
#pragma unroll
            for (int ni = 0; ni < 4; ni++)
                acc[mi][ni] = __builtin_amdgcn_mfma_f32_16x16x32_f16(ah[mi], bh[ni], acc[mi][ni], 0, 0, 0);
    }
    // ---- fused cross soft-DTW epilogue (scaled domain) ----
    int jj = lane & 31;
    int hh = lane >> 5;  // which query of the pair this 32-lane half handles
    float xreg, cj0, cj1;
    {
        const float* xp = x2part + ((size_t)(q0 + hh) * 32 + jj) * 8;
        const float* y0 = y2part + ((size_t)p0 * 32 + jj) * 8;
        const float* y1 = y2part + ((size_t)(p0 + 1) * 32 + jj) * 8;
        float sx = 0.f, s0 = 0.f, s1 = 0.f;
#pragma unroll
        for (int p = 0; p < 8; p++) {
            sx += xp[p];
            s0 += y0[p];
            s1 += y1[p];
        }
        xreg = sx;
        cj0 = s0;
        cj1 = s1;
    }
#pragma unroll
    for (int pp = 0; pp < 2; pp++) {
        __syncthreads();  // protect prior pass reads before overwriting dmat
#pragma unroll
        for (int qi = 0; qi < 2; qi++)
#pragma unroll
            for (int m2 = 0; m2 < 2; m2++)
#pragma unroll
                for (int nn = 0; nn < 2; nn++)
#pragma unroll
                    for (int j = 0; j < 4; j++)
                        dmat[wid][qi][m2 * 16 + g * 4 + j][nn * 16 + r] =
                            acc[qi * 2 + m2][pp * 2 + nn][j];
        __syncthreads();
        float cjv = pp ? cj1 : cj0;
        const float* cm = &dmat[wid][hh][0][0];
        float my_prev = BIG, my_prev2 = BIG;
        int ip = 0 - jj; ip = ip < 0 ? 0 : ip;
        float nxt = cm[ip * 32 + jj];
        for (int k = 0; k < 63; k++) {
            float cur = nxt;
            int in = k + 1 - jj; in = in < 0 ? 0 : (in > 31 ? 31 : in);
            nxt = cm[in * 32 + jj];  // bank = jj: conflict-free
            float lp = __shfl_up(my_prev, 1, 32);
            float dg = __shfl_up(my_prev2, 1, 32);
            if (jj == 0) { lp = BIG; dg = (k == 0) ? 0.f : BIG; }
            float up = my_prev;
            int i = k - jj;
            float ai = __shfl(xreg, i & 31, 32);
            float ds = (ai + cjv - 2.0f * cur) * INVG;  // off-critical-path scale
            float mn = fminf(dg, fminf(up, lp));
            float ssum = __expf(mn - dg) + __expf(mn - up) + __expf(mn - lp);
            float rv = ds + mn - __logf(ssum);
            bool act = (i >= 0) && (i < 32);
            my_prev2 = my_prev;
            my_prev = act ? rv : my_prev;
        }
        if (jj == 31) dxy[(size_t)(q0 + hh) * NCLASS + p0 + pp] = my_prev * GAMMA;
    }
}

// ---------------- wavefront soft-DTW for the 520 self matrices (scaled domain) ----
__global__ __launch_bounds__(256) void softdtw_self_kernel(
        const float* __restrict__ gxx, const float* __restrict__ gyy,
        float* __restrict__ dxx, float* __restrict__ dyy) {
    int tid = threadIdx.x;
    int jj = tid & 31;
    int mm = blockIdx.x * 8 + (tid >> 5);
    bool valid = mm < NSELF;
    int mmc = valid ? mm : 0;
    const float* base = (mmc < NQ) ? gxx + (size_t)mmc * (T * T)
                                   : gyy + (size_t)(mmc - NQ) * (T * T);
    float* outp = (mmc < NQ) ? dxx + mmc : dyy + (mmc - NQ);
    float cjv = base[jj * 33];  // diag (j,j)
    float xreg = cjv;
    float my_prev = BIG, my_prev2 = BIG;
    int ip = 0 - jj; ip = ip < 0 ? 0 : ip;
    float nxt = base[ip * T + jj];
    for (int k = 0; k < 63; k++) {
        float cur = nxt;
        int in = k + 1 - jj; in = in < 0 ? 0 : (in > 31 ? 31 : in);
        nxt = base[in * T + jj];
        float lp = __shfl_up(my_prev, 1, 32);
        float dg = __shfl_up(my_prev2, 1, 32);
        if (jj == 0) { lp = BIG; dg = (k == 0) ? 0.f : BIG; }
        float up = my_prev;
        int i = k - jj;
        float ai = __shfl(xreg, i & 31, 32);
        float ds = (ai + cjv - 2.0f * cur) * INVG;
        float mn = fminf(dg, fminf(up, lp));
        float ssum = __expf(mn - dg) + __expf(mn - up) + __expf(mn - lp);
        float rv = ds + mn - __logf(ssum);
        bool act = (i >= 0) && (i < 32);
        my_prev2 = my_prev;
        my_prev = act ? rv : my_prev;
    }
    if (jj == 31 && valid) *outp = my_prev * GAMMA;
}

// ---------------- finalize: dist, log-softmax, loss, acc ----------------
__global__ __launch_bounds__(512) void finalize_kernel(const float* __restrict__ dxy,
                                                       const float* __restrict__ dxx,
                                                       const float* __restrict__ dyy,
                                                       float* __restrict__ out) {
    __shared__ float sl[512];
    __shared__ float sa[512];
    int q = threadIdx.x;
    float bl = 0.f, fl = 0.f;
    if (q < NQ) {
        float dxxq = dxx[q];
        int cq = q / NQPC;
        float dd[NCLASS];
#pragma unroll
        for (int m = 0; m < NCLASS; m++)
            dd[m] = dxy[q * NCLASS + m] - 0.5f * (dxxq + dyy[m]);
        float best = dd[0];
        int bi = 0;
#pragma unroll
        for (int m = 1; m < NCLASS; m++) {
            if (dd[m] < best) { best = dd[m]; bi = m; }
        }
        float s = 0.f;
        float dcq = dd[0];
#pragma unroll
        for (int m = 0; m < NCLASS; m++) {
            s += __expf(best - dd[m]);
            if (m == cq) dcq = dd[m];
        }
        float lse = __logf(s) - best;
        bl = dcq + lse;
        out[2 + q] = bl;
        fl = (bi == cq) ? 1.f : 0.f;
    }
    sl[threadIdx.x] = bl;
    sa[threadIdx.x] = fl;
    __syncthreads();
    for (int off = 256; off; off >>= 1) {
        if (threadIdx.x < off) {
            sl[threadIdx.x] += sl[threadIdx.x + off];
            sa[threadIdx.x] += sa[threadIdx.x + off];
        }
        __syncthreads();
    }
    if (threadIdx.x == 0) {
        out[0] = sl[0] / (float)NQ;
        out[1] = sa[0] / (float)NQ;
    }
}

extern "C" void kernel_launch(void* const* d_in, const int* in_sizes, int n_in,
                              void* d_out, int out_size, void* d_ws, size_t ws_size,
                              hipStream_t stream) {
    const float* inp = (const float*)d_in[0];
    const int* target = (const int*)d_in[1];
    float* out = (float*)d_out;
    char* ws = (char*)d_ws;

    size_t off = 0;
    auto carve = [&](size_t bytes) {
        void* p = ws + off;
        off = (off + bytes + 255) & ~(size_t)255;
        return p;
    };
    int* order = (int*)carve(NTOT * sizeof(int));
    int* qsrc = (int*)carve(NQ * sizeof(int));
    float* x2part = (float*)carve((size_t)NQROWS * 8 * sizeof(float));  // 512 KB
    float* y2part = (float*)carve((size_t)NPROWS * 8 * sizeof(float));  // 20 KB
    float* gxx = (float*)carve((size_t)NQ * T * T * sizeof(float));
    float* gyy = (float*)carve((size_t)NCLASS * T * T * sizeof(float));
    float* dxy = (float*)carve((size_t)NQ * NCLASS * sizeof(float));
    float* dxx = (float*)carve((size_t)NQ * sizeof(float));
    float* dyy = (float*)carve((size_t)NCLASS * sizeof(float));
    half8* Ah = (half8*)carve((size_t)NQ * SAMP_STRIDE * 16);  // 65.5 MB per-query
    half8* Bh = (half8*)carve((size_t)(C / 8) * NPROWS * 16);  // 2.6 MB (L2-resident)
    (void)ws_size;

    sort_kernel<<<1, 640, 0, stream>>>(target, order, qsrc);
    stage_kernel<<<STAGE_BLKS_A + STAGE_BLKS_B, 256, 0, stream>>>(inp, qsrc, order, Ah, Bh,
                                                                  x2part, y2part);
    gemm_syrk_kernel<<<SYRK_BLKS_PAD + GEMM_BLKS, 256, 0, stream>>>(Ah, Bh, x2part, y2part,
                                                                    dxy, gxx, gyy);
    softdtw_self_kernel<<<(NSELF + 7) / 8, 256, 0, stream>>>(gxx, gyy, dxx, dyy);
    finalize_kernel<<<1, 512, 0, stream>>>(dxy, dxx, dyy, out);
}

// Round 23
// 158.945 us; speedup vs baseline: 1.3175x; 1.0193x over previous
//
#include <hip/hip_runtime.h>

#define T 32
#define C 2048
#define NTOT 600
#define NCLASS 20
#define NSUP 5
#define PER 30
#define NQPC 25
#define NQ 500
#define NQROWS (NQ * T)      // 16000
#define NPROWS (NCLASS * T)  // 640
#define GAMMA 0.1f
#define INVG 10.0f
#define BIG 1e10f
#define NSELF (NQ + NCLASS)  // 520
#define GEMM_BLKS 625
#define SYRK_BLKS_PAD 136  // multiple of 8 so gemm swizzle sees o%8 unchanged
#define SAMP_STRIDE 8192   // half8 per staged query sample: 256 chunks x 32 rows
#define STAGE_BLKS_A 2000  // (500*32/16 row-tiles) x 2 col-halves
#define STAGE_BLKS_B 80    // (640/16) x 2
#define LDS_PITCH 33       // half8 per LDS row (32 chunks + 1 pad)

typedef __fp16 half8 __attribute__((ext_vector_type(8)));
typedef __fp16 half4 __attribute__((ext_vector_type(4)));
typedef float f32x4 __attribute__((ext_vector_type(4)));

// ---------------- parallel stable counting sort (1 block) ----------------
__global__ __launch_bounds__(640) void sort_kernel(const int* __restrict__ target,
                                                   int* __restrict__ order,
                                                   int* __restrict__ qsrc) {
    __shared__ int tgt[NTOT];
    __shared__ int offs[NCLASS];
    __shared__ int ordl[NTOT];
    int tid = threadIdx.x;
    if (tid < NTOT) tgt[tid] = target[tid];
    __syncthreads();
    if (tid < NCLASS) {
        int o = 0;
        for (int i = 0; i < NTOT; i++) o += (tgt[i] < tid) ? 1 : 0;
        offs[tid] = o;
    }
    __syncthreads();
    if (tid < NTOT) {
        int c = tgt[tid];
        int rank = 0;
        for (int k = 0; k < NTOT; k++) rank += (k < tid && tgt[k] == c) ? 1 : 0;
        ordl[offs[c] + rank] = tid;
    }
    __syncthreads();
    if (tid < NTOT) order[tid] = ordl[tid];
    if (tid < NQ) qsrc[tid] = ordl[(tid / NQPC) * PER + NSUP + (tid % NQPC)];
}

// ---------------- staging: gather + f16 round + LDS transpose + norm partials -----
__global__ __launch_bounds__(256) void stage_kernel(const float* __restrict__ inp,
                                                    const int* __restrict__ qsrc,
                                                    const int* __restrict__ order,
                                                    half8* __restrict__ Ah,
                                                    half8* __restrict__ Bh,
                                                    float* __restrict__ x2part,
                                                    float* __restrict__ y2part) {
    __shared__ half8 lds[4][16][LDS_PITCH];  // 33.8 KB
    int tid = threadIdx.x;
    int lane = tid & 63, w = tid >> 6;
    int bid = blockIdx.x;
    bool isA = bid < STAGE_BLKS_A;
    int b = isA ? bid : bid - STAGE_BLKS_A;
    int rowblk = b >> 1, half = b & 1;
    int row0 = rowblk * 16;
    int colbase = half * 1024 + w * 256;  // this wave's float-col window
    int pidx = half * 4 + w;              // partial slot 0..7
    if (isA) {
        int q = row0 >> 5, rowin0 = row0 & 31;  // 16-row tile within one query sample
        const float* sbase = inp + (size_t)qsrc[q] * (T * C) + (size_t)rowin0 * C +
                             colbase + lane * 4;
#pragma unroll
        for (int rr = 0; rr < 16; rr++) {
            float4 v = *(const float4*)(sbase + (size_t)rr * C);
            half4 hv = {(__fp16)v.x, (__fp16)v.y, (__fp16)v.z, (__fp16)v.w};
            ((half4*)&lds[w][rr][0])[lane] = hv;  // contiguous 512B per wave
            float fx = (float)hv[0], fy = (float)hv[1], fz = (float)hv[2], fw = (float)hv[3];
            float s = fx * fx + fy * fy + fz * fz + fw * fw;
#pragma unroll
            for (int d = 1; d < 64; d <<= 1) s += __shfl_xor(s, d);
            if (lane == 0) x2part[(size_t)(row0 + rr) * 8 + pidx] = s;
        }
        __syncthreads();
        int chunkbase = half * 128 + w * 32;
        half8* dst = Ah + (size_t)q * SAMP_STRIDE + rowin0;
#pragma unroll
        for (int c = 0; c < 8; c++) {
            int idx = c * 64 + lane;         // 0..511
            int ch = idx >> 4, row = idx & 15;
            dst[(size_t)(chunkbase + ch) * 32 + row] = lds[w][row][ch];
        }
    } else {
#pragma unroll
        for (int rr = 0; rr < 16; rr++) {
            int rg = row0 + rr;
            int cls = rg >> 5, trow = rg & 31;
            const float* base = inp + (size_t)trow * C + colbase + lane * 4;
            float4 a = *(const float4*)(base + (size_t)order[cls * PER + 0] * (T * C));
            float4 b4 = *(const float4*)(base + (size_t)order[cls * PER + 1] * (T * C));
            float4 c = *(const float4*)(base + (size_t)order[cls * PER + 2] * (T * C));
            float4 d = *(const float4*)(base + (size_t)order[cls * PER + 3] * (T * C));
            float4 e = *(const float4*)(base + (size_t)order[cls * PER + 4] * (T * C));
            float4 m;
            m.x = (a.x + b4.x + c.x + d.x + e.x) * 0.2f;
            m.y = (a.y + b4.y + c.y + d.y + e.y) * 0.2f;
            m.z = (a.z + b4.z + c.z + d.z + e.z) * 0.2f;
            m.w = (a.w + b4.w + c.w + d.w + e.w) * 0.2f;
            half4 hv = {(__fp16)m.x, (__fp16)m.y, (__fp16)m.z, (__fp16)m.w};
            ((half4*)&lds[w][rr][0])[lane] = hv;
            float fx = (float)hv[0], fy = (float)hv[1], fz = (float)hv[2], fw = (float)hv[3];
            float s = fx * fx + fy * fy + fz * fz + fw * fw;
#pragma unroll
            for (int dd = 1; dd < 64; dd <<= 1) s += __shfl_xor(s, dd);
            if (lane == 0) y2part[(size_t)rg * 8 + pidx] = s;
        }
        __syncthreads();
        int chunkbase = half * 128 + w * 32;
#pragma unroll
        for (int c = 0; c < 8; c++) {
            int idx = c * 64 + lane;
            int ch = idx >> 4, row = idx & 15;
            Bh[(size_t)(chunkbase + ch) * NPROWS + row0 + row] = lds[w][row][ch];
        }
    }
}

// ---------------- merged: SYRK + GEMM with FUSED cross soft-DTW epilogue ----------
__global__ __launch_bounds__(256) void gemm_syrk_kernel(const half8* __restrict__ Ah,
                                                        const half8* __restrict__ Bh,
                                                        const float* __restrict__ x2part,
                                                        const float* __restrict__ y2part,
                                                        float* __restrict__ dxy,
                                                        float* __restrict__ gxx,
                                                        float* __restrict__ gyy) {
    __shared__ float dmat[4][2][32][32];  // per-wave 2-matrix DTW tile, 32 KB
    int tid = threadIdx.x, lane = tid & 63, wid = tid >> 6;
    int o = blockIdx.x;
    int g = lane >> 4, r = lane & 15;
    if (o < SYRK_BLKS_PAD) {
        // ---- SYRK path: one wave per 32x32 Gram matrix (short blocks first) ----
        int ww = o * 4 + wid;
        if (ww >= NSELF) return;
        f32x4 acc[2][2];
        f32x4 zero = {0.f, 0.f, 0.f, 0.f};
        acc[0][0] = zero; acc[0][1] = zero; acc[1][0] = zero; acc[1][1] = zero;
        if (ww < NQ) {
            const half8* p = Ah + (size_t)ww * SAMP_STRIDE + g * 32 + r;
            float* outp = gxx + (size_t)ww * (T * T);
            for (int t = 0; t < C / 32; t++) {
                half8 h0 = p[0], h1 = p[16];
                p += 128;  // next 4 chunks
                acc[0][0] = __builtin_amdgcn_mfma_f32_16x16x32_f16(h0, h0, acc[0][0], 0, 0, 0);
                acc[0][1] = __builtin_amdgcn_mfma_f32_16x16x32_f16(h0, h1, acc[0][1], 0, 0, 0);
                acc[1][0] = __builtin_amdgcn_mfma_f32_16x16x32_f16(h1, h0, acc[1][0], 0, 0, 0);
                acc[1][1] = __builtin_amdgcn_mfma_f32_16x16x32_f16(h1, h1, acc[1][1], 0, 0, 0);
            }
#pragma unroll
            for (int mi = 0; mi < 2; mi++)
#pragma unroll
                for (int ni = 0; ni < 2; ni++)
#pragma unroll
                    for (int j = 0; j < 4; j++)
                        outp[(mi * 16 + g * 4 + j) * T + ni * 16 + r] = acc[mi][ni][j];
        } else {
            int row0 = (ww - NQ) * 32;
            float* outp = gyy + (size_t)(ww - NQ) * (T * T);
            for (int t = 0; t < C / 32; t++) {
                size_t base = (size_t)(t * 4 + g) * NPROWS + row0 + r;
                half8 h0 = Bh[base], h1 = Bh[base + 16];
                acc[0][0] = __builtin_amdgcn_mfma_f32_16x16x32_f16(h0, h0, acc[0][0], 0, 0, 0);
                acc[0][1] = __builtin_amdgcn_mfma_f32_16x16x32_f16(h0, h1, acc[0][1], 0, 0, 0);
                acc[1][0] = __builtin_amdgcn_mfma_f32_16x16x32_f16(h1, h0, acc[1][0], 0, 0, 0);
                acc[1][1] = __builtin_amdgcn_mfma_f32_16x16x32_f16(h1, h1, acc[1][1], 0, 0, 0);
            }
#pragma unroll
            for (int mi = 0; mi < 2; mi++)
#pragma unroll
                for (int ni = 0; ni < 2; ni++)
#pragma unroll
                    for (int j = 0; j < 4; j++)
                        outp[(mi * 16 + g * 4 + j) * T + ni * 16 + r] = acc[mi][ni][j];
        }
        return;
    }
    // ---- GEMM path: dots = Ah*Bh^T, 1 MFMA term, register-direct, deep unroll ----
    int oo = o - SYRK_BLKS_PAD;  // 0..624; SYRK_BLKS_PAD%8==0 keeps oo%8==o%8
    int xcd = oo & 7, slot = oo >> 3;
    int v = (xcd < 1 ? xcd * 79 : 79 + (xcd - 1) * 78) + slot;  // bijective over 625=8*78+1
    int bm = v / 5, bn = v % 5;
    int wr = wid >> 1, wc = wid & 1;
    int m0 = bm * 128 + wr * 64, n0 = bn * 128 + wc * 64;  // this wave's 64x64 tile
    int q0 = m0 >> 5;   // two query samples
    int p0 = n0 >> 5;   // two protos
    const half8* pA0 = Ah + (size_t)q0 * SAMP_STRIDE + g * 32 + r;
    const half8* pA1 = pA0 + SAMP_STRIDE;
    const half8* pB = Bh + (size_t)g * NPROWS + n0 + r;
    f32x4 acc[4][4];
    f32x4 zero = {0.f, 0.f, 0.f, 0.f};
#pragma unroll
    for (int mi = 0; mi < 4; mi++)
#pragma unroll
        for (int ni = 0; ni < 4; ni++) acc[mi][ni] = zero;
#pragma unroll 4
    for (int t = 0; t < C / 32; t++) {
        half8 ah[4], bh[4];
        ah[0] = pA0[0];
        ah[1] = pA0[16];
        ah[2] = pA1[0];
        ah[3] = pA1[16];
#pragma unroll
        for (int i = 0; i < 4; i++) bh[i] = pB[i * 16];
        pA0 += 128;
        pA1 += 128;
        pB += 4 * NPROWS;
#pragma unroll
        for (int mi = 0; mi < 4; mi++)
#pragma unroll
            for (int ni = 0; ni < 4; ni++)
                acc[mi][ni] = __builtin_amdgcn_mfma_f32_16x16x32_f16(ah[mi], bh[ni], acc[mi][ni], 0, 0, 0);
    }
    // ---- fused cross soft-DTW epilogue (scaled domain) ----
    int jj = lane & 31;
    int hh = lane >> 5;  // which query of the pair this 32-lane half handles
    float xreg, cj0, cj1;
    {
        const float* xp = x2part + ((size_t)(q0 + hh) * 32 + jj) * 8;
        const float* y0 = y2part + ((size_t)p0 * 32 + jj) * 8;
        const float* y1 = y2part + ((size_t)(p0 + 1) * 32 + jj) * 8;
        float sx = 0.f, s0 = 0.f, s1 = 0.f;
#pragma unroll
        for (int p = 0; p < 8; p++) {
            sx += xp[p];
            s0 += y0[p];
            s1 += y1[p];
        }
        xreg = sx;
        cj0 = s0;
        cj1 = s1;
    }
#pragma unroll
    for (int pp = 0; pp < 2; pp++) {
        __syncthreads();  // protect prior pass reads before overwriting dmat
#pragma unroll
        for (int qi = 0; qi < 2; qi++)
#pragma unroll
            for (int m2 = 0; m2 < 2; m2++)
#pragma unroll
                for (int nn = 0; nn < 2; nn++)
#pragma unroll
                    for (int j = 0; j < 4; j++)
                        dmat[wid][qi][m2 * 16 + g * 4 + j][nn * 16 + r] =
                            acc[qi * 2 + m2][pp * 2 + nn][j];
        __syncthreads();
        float cjv = pp ? cj1 : cj0;
        const float* cm = &dmat[wid][hh][0][0];
        float my_prev = BIG, my_prev2 = BIG;
        int ip = 0 - jj; ip = ip < 0 ? 0 : ip;
        float nxt = cm[ip * 32 + jj];
        for (int k = 0; k < 63; k++) {
            float cur = nxt;
            int in = k + 1 - jj; in = in < 0 ? 0 : (in > 31 ? 31 : in);
            nxt = cm[in * 32 + jj];  // bank = jj: conflict-free
            float lp = __shfl_up(my_prev, 1, 32);
            float dg = __shfl_up(my_prev2, 1, 32);
            if (jj == 0) { lp = BIG; dg = (k == 0) ? 0.f : BIG; }
            float up = my_prev;
            int i = k - jj;
            float ai = __shfl(xreg, i & 31, 32);
            float ds = (ai + cjv - 2.0f * cur) * INVG;  // off-critical-path scale
            float mn = fminf(dg, fminf(up, lp));
            float ssum = __expf(mn - dg) + __expf(mn - up) + __expf(mn - lp);
            float rv = ds + mn - __logf(ssum);
            bool act = (i >= 0) && (i < 32);
            my_prev2 = my_prev;
            my_prev = act ? rv : my_prev;
        }
        if (jj == 31) dxy[(size_t)(q0 + hh) * NCLASS + p0 + pp] = my_prev * GAMMA;
    }
}

// ---------------- wavefront soft-DTW for the 520 self matrices (scaled domain) ----
__global__ __launch_bounds__(256) void softdtw_self_kernel(
        const float* __restrict__ gxx, const float* __restrict__ gyy,
        float* __restrict__ dxx, float* __restrict__ dyy) {
    int tid = threadIdx.x;
    int jj = tid & 31;
    int mm = blockIdx.x * 8 + (tid >> 5);
    bool valid = mm < NSELF;
    int mmc = valid ? mm : 0;
    const float* base = (mmc < NQ) ? gxx + (size_t)mmc * (T * T)
                                   : gyy + (size_t)(mmc - NQ) * (T * T);
    float* outp = (mmc < NQ) ? dxx + mmc : dyy + (mmc - NQ);
    float cjv = base[jj * 33];  // diag (j,j)
    float xreg = cjv;
    float my_prev = BIG, my_prev2 = BIG;
    int ip = 0 - jj; ip = ip < 0 ? 0 : ip;
    float nxt = base[ip * T + jj];
    for (int k = 0; k < 63; k++) {
        float cur = nxt;
        int in = k + 1 - jj; in = in < 0 ? 0 : (in > 31 ? 31 : in);
        nxt = base[in * T + jj];
        float lp = __shfl_up(my_prev, 1, 32);
        float dg = __shfl_up(my_prev2, 1, 32);
        if (jj == 0) { lp = BIG; dg = (k == 0) ? 0.f : BIG; }
        float up = my_prev;
        int i = k - jj;
        float ai = __shfl(xreg, i & 31, 32);
        float ds = (ai + cjv - 2.0f * cur) * INVG;
        float mn = fminf(dg, fminf(up, lp));
        float ssum = __expf(mn - dg) + __expf(mn - up) + __expf(mn - lp);
        float rv = ds + mn - __logf(ssum);
        bool act = (i >= 0) && (i < 32);
        my_prev2 = my_prev;
        my_prev = act ? rv : my_prev;
    }
    if (jj == 31 && valid) *outp = my_prev * GAMMA;
}

// ---------------- finalize: dist, log-softmax, loss, acc ----------------
__global__ __launch_bounds__(512) void finalize_kernel(const float* __restrict__ dxy,
                                                       const float* __restrict__ dxx,
                                                       const float* __restrict__ dyy,
                                                       float* __restrict__ out) {
    __shared__ float sl[512];
    __shared__ float sa[512];
    int q = threadIdx.x;
    float bl = 0.f, fl = 0.f;
    if (q < NQ) {
        float dxxq = dxx[q];
        int cq = q / NQPC;
        float dd[NCLASS];
#pragma unroll
        for (int m = 0; m < NCLASS; m++)
            dd[m] = dxy[q * NCLASS + m] - 0.5f * (dxxq + dyy[m]);
        float best = dd[0];
        int bi = 0;
#pragma unroll
        for (int m = 1; m < NCLASS; m++) {
            if (dd[m] < best) { best = dd[m]; bi = m; }
        }
        float s = 0.f;
        float dcq = dd[0];
#pragma unroll
        for (int m = 0; m < NCLASS; m++) {
            s += __expf(best - dd[m]);
            if (m == cq) dcq = dd[m];
        }
        float lse = __logf(s) - best;
        bl = dcq + lse;
        out[2 + q] = bl;
        fl = (bi == cq) ? 1.f : 0.f;
    }
    sl[threadIdx.x] = bl;
    sa[threadIdx.x] = fl;
    __syncthreads();
    for (int off = 256; off; off >>= 1) {
        if (threadIdx.x < off) {
            sl[threadIdx.x] += sl[threadIdx.x + off];
            sa[threadIdx.x] += sa[threadIdx.x + off];
        }
        __syncthreads();
    }
    if (threadIdx.x == 0) {
        out[0] = sl[0] / (float)NQ;
        out[1] = sa[0] / (float)NQ;
    }
}

extern "C" void kernel_launch(void* const* d_in, const int* in_sizes, int n_in,
                              void* d_out, int out_size, void* d_ws, size_t ws_size,
                              hipStream_t stream) {
    const float* inp = (const float*)d_in[0];
    const int* target = (const int*)d_in[1];
    float* out = (float*)d_out;
    char* ws = (char*)d_ws;

    size_t off = 0;
    auto carve = [&](size_t bytes) {
        void* p = ws + off;
        off = (off + bytes + 255) & ~(size_t)255;
        return p;
    };
    int* order = (int*)carve(NTOT * sizeof(int));
    int* qsrc = (int*)carve(NQ * sizeof(int));
    float* x2part = (float*)carve((size_t)NQROWS * 8 * sizeof(float));  // 512 KB
    float* y2part = (float*)carve((size_t)NPROWS * 8 * sizeof(float));  // 20 KB
    float* gxx = (float*)carve((size_t)NQ * T * T * sizeof(float));
    float* gyy = (float*)carve((size_t)NCLASS * T * T * sizeof(float));
    float* dxy = (float*)carve((size_t)NQ * NCLASS * sizeof(float));
    float* dxx = (float*)carve((size_t)NQ * sizeof(float));
    float* dyy = (float*)carve((size_t)NCLASS * sizeof(float));
    half8* Ah = (half8*)carve((size_t)NQ * SAMP_STRIDE * 16);  // 65.5 MB per-query
    half8* Bh = (half8*)carve((size_t)(C / 8) * NPROWS * 16);  // 2.6 MB (L2-resident)
    (void)ws_size;

    sort_kernel<<<1, 640, 0, stream>>>(target, order, qsrc);
    stage_kernel<<<STAGE_BLKS_A + STAGE_BLKS_B, 256, 0, stream>>>(inp, qsrc, order, Ah, Bh,
                                                                  x2part, y2part);
    gemm_syrk_kernel<<<SYRK_BLKS_PAD + GEMM_BLKS, 256, 0, stream>>>(Ah, Bh, x2part, y2part,
                                                                    dxy, gxx, gyy);
    softdtw_self_kernel<<<(NSELF + 7) / 8, 256, 0, stream>>>(gxx, gyy, dxx, dyy);
    finalize_kernel<<<1, 512, 0, stream>>>(dxy, dxx, dyy, out);
}